// Round 11
// baseline (3737.943 us; speedup 1.0000x reference)
//
#include <hip/hip_runtime.h>
#include <hip/hip_bf16.h>
#include <math.h>

#define SEQ 70
#define HID 230
#define G3  690
#define EMBD 50
#define DIN 60
#define NTOT 2048
#define NREL 100
#define NBAG 64
#define BAGSZ 32
#define PDIM 5
#define MB 4      // sentences per GRU block -> 1024 blocks = 4 blocks/CU = 4 waves/SIMD
#define KU 10     // k-rows per rolling weight buffer
#define KTOT 290  // DIN + HID unified K stream
#define SROWS 292 // KTOT + 2 pad rows for row-prefetch overrun

// ---------------- prep kernels ----------------

__global__ void k_zero(float* p, long n) {
    long i = (long)blockIdx.x * 256 + threadIdx.x;
    if (i < n) p[i] = 0.f;
}

__global__ void k_embed(const int* __restrict__ sent, const int* __restrict__ p1,
                        const int* __restrict__ p2,  const float* __restrict__ wemb,
                        const float* __restrict__ t1, const float* __restrict__ t2,
                        float* __restrict__ emb) {
    long idx = (long)blockIdx.x * 256 + threadIdx.x;
    long total = (long)NTOT * SEQ * DIN;
    if (idx >= total) return;
    int nt = (int)(idx / DIN);
    int j  = (int)(idx % DIN);
    float v;
    if (j < EMBD)            v = wemb[(long)sent[nt] * EMBD + j];
    else if (j < EMBD + PDIM) v = t1[p1[nt] * PDIM + (j - EMBD)];
    else                      v = t2[p2[nt] * PDIM + (j - EMBD - PDIM)];
    emb[idx] = v;
}

// in[g*K+k] -> out[k*G+g]
__global__ void k_transpose(const float* __restrict__ in, float* __restrict__ out,
                            int G, int K) {
    int idx = blockIdx.x * 256 + threadIdx.x;
    if (idx >= G * K) return;
    int g = idx / K, k = idx % K;
    out[k * G + g] = in[idx];
}

// ---------------- GRU (both directions in one launch) ----------------
// grid = (NTOT/MB)*2 = 1024 blocks of 256 threads -> 4 blocks/CU = 16 waves/CU
// = 4 waves/SIMD (the TLP every round since R2 lacked). blockIdx.x&1 = dir.
// Thread tid < HID owns gates (tid, HID+tid, 2*HID+tid) -> thread-local combine.
// SCALING LAWS (R9 counters): per CU-step, LDS instr (4640) and FMA cycles
// (27.8k/SIMD) are invariant in MB; weight-L2 bytes = 12.8/MB MB; waves/SIMD
// = 16/MB. MB=4 trades 2x weight-L2 traffic (L1-absorbed partly: co-resident
// blocks read identical streams) for 2x TLP, and the thin kernel (~12 accs +
// 30 weight regs) fits the 128-VGPR cap with ZERO spill (R5-R8 blocker).
// Rolling single weight buffer: after FMAs consume w[UE] of block kb, the same
// reg is reloaded with block kb+1 row UE (10-row lead ~ covers L2 latency);
// epilogue wraps prefetch to block 0 (weights t-invariant) -> no per-step stall.
// Old h is re-read from the thread's own LDS row (no hprev regs).
// Unified K stream: wcat rows 0..59 = Wih^T, rows 60..289 = Whh^T.
// s_s rows 0..59 = emb tile (staged per t), rows 60..289 = h state.
// LDS rows depth-2 rotated (ra0/rb0). All register indices compile-time.
// tup must be zeroed beforehand; both directions atomicAdd into it.

#define ROWLD(R0, kk) { R0 = *(const float4*)s_s[kk]; }

#define FMA4(WR,WZ,WN, Q, AR,AZ,AN) \
    AR[0]=fmaf(WR,Q.x,AR[0]); AZ[0]=fmaf(WZ,Q.x,AZ[0]); AN[0]=fmaf(WN,Q.x,AN[0]); \
    AR[1]=fmaf(WR,Q.y,AR[1]); AZ[1]=fmaf(WZ,Q.y,AZ[1]); AN[1]=fmaf(WN,Q.y,AN[1]); \
    AR[2]=fmaf(WR,Q.z,AR[2]); AZ[2]=fmaf(WZ,Q.z,AZ[2]); AN[2]=fmaf(WN,Q.z,AN[2]); \
    AR[3]=fmaf(WR,Q.w,AR[3]); AZ[3]=fmaf(WZ,Q.w,AZ[3]); AN[3]=fmaf(WN,Q.w,AN[3]);

// two k-steps with rolling weight prefetch: consume w[UE] for block KB, then
// reload the SAME slot with block KB+1 row UE (distance 10 rows).
#define U2R(KB, UE, AR,AZ,AN) \
    FMA4(wR[UE],wZ[UE],wN[UE], ra0, AR,AZ,AN); \
    ROWLD(ra0, (KB)*KU+(UE)+2); \
    { int _kk = (((KB)+1)*KU + (UE)) * G3; wR[UE]=pr[_kk]; wZ[UE]=pz[_kk]; wN[UE]=pn[_kk]; } \
    FMA4(wR[UE+1],wZ[UE+1],wN[UE+1], rb0, AR,AZ,AN); \
    ROWLD(rb0, (KB)*KU+(UE)+3); \
    { int _kk = (((KB)+1)*KU + (UE)+1) * G3; wR[UE+1]=pr[_kk]; wZ[UE+1]=pz[_kk]; wN[UE+1]=pn[_kk]; }

// epilogue variant: wrap the weight prefetch to block 0 (for next timestep)
#define U2W(KB, UE, AR,AZ,AN) \
    FMA4(wR[UE],wZ[UE],wN[UE], ra0, AR,AZ,AN); \
    ROWLD(ra0, (KB)*KU+(UE)+2); \
    { int _kk = (UE) * G3; wR[UE]=pr[_kk]; wZ[UE]=pz[_kk]; wN[UE]=pn[_kk]; } \
    FMA4(wR[UE+1],wZ[UE+1],wN[UE+1], rb0, AR,AZ,AN); \
    ROWLD(rb0, (KB)*KU+(UE)+3); \
    { int _kk = ((UE)+1) * G3; wR[UE+1]=pr[_kk]; wZ[UE+1]=pz[_kk]; wN[UE+1]=pn[_kk]; }

#define BLK10R(KB, AR,AZ,AN) \
    U2R(KB, 0, AR,AZ,AN) U2R(KB, 2, AR,AZ,AN) U2R(KB, 4, AR,AZ,AN) \
    U2R(KB, 6, AR,AZ,AN) U2R(KB, 8, AR,AZ,AN)

#define BLK10W(KB, AR,AZ,AN) \
    U2W(KB, 0, AR,AZ,AN) U2W(KB, 2, AR,AZ,AN) U2W(KB, 4, AR,AZ,AN) \
    U2W(KB, 6, AR,AZ,AN) U2W(KB, 8, AR,AZ,AN)

__global__ __launch_bounds__(256, 4) void k_gru(
    const float* __restrict__ emb,
    const float* __restrict__ wcat_f, const float* __restrict__ bih_f, const float* __restrict__ bhh_f,
    const float* __restrict__ wcat_b, const float* __restrict__ bih_b, const float* __restrict__ bhh_b,
    float* __restrict__ tup) {

    const bool rev = blockIdx.x & 1;
    const int  n0  = (blockIdx.x >> 1) * MB;
    const float* wcat = rev ? wcat_b : wcat_f;
    const float* bih  = rev ? bih_b  : bih_f;
    const float* bhh  = rev ? bhh_b  : bhh_f;
    const int tid = threadIdx.x;
    const bool act = tid < HID;

    __shared__ float s_s[SROWS][MB];   // 4672 B: rows 0..59 = e, 60..289 = h

    for (int i = tid; i < SROWS * MB; i += 256) ((float*)s_s)[i] = 0.f;

    float bir = 0.f, biz = 0.f, bin_ = 0.f, bhr = 0.f, bhz = 0.f, bhn = 0.f;
    if (act) {
        bir = bih[tid]; biz = bih[HID + tid]; bin_ = bih[2 * HID + tid];
        bhr = bhh[tid]; bhz = bhh[HID + tid]; bhn = bhh[2 * HID + tid];
    }

    const float* pr = wcat + tid;            // row k at pr[k*G3]
    const float* pz = wcat + HID + tid;
    const float* pn = wcat + 2 * HID + tid;

    // rolling weight buffer: preload block 0 once; steady-state refills happen
    // inside U2R/U2W with 10-row lead. Weights are t-invariant.
    float wR[KU], wZ[KU], wN[KU];
    if (act) {
#pragma unroll
        for (int u = 0; u < KU; ++u) {
            int kk = u * G3; wR[u] = pr[kk]; wZ[u] = pz[kk]; wN[u] = pn[kk];
        }
    }

    __syncthreads();

    for (int t = 0; t < SEQ; ++t) {
        const int tt = rev ? (SEQ - 1 - t) : t;

        // stage emb tile into s_s rows 0..59 (240 elems, 256 threads)
        if (tid < DIN * MB) {
            int n = tid / DIN, k = tid - n * DIN;
            s_s[k][n] = emb[((long)(n0 + n) * SEQ + tt) * DIN + k];
        }
        __syncthreads();   // A: e rows staged, h rows published

        float ar[MB], az[MB], an[MB], hr[MB], hz[MB], hn[MB];
        if (act) {
#pragma unroll
            for (int n = 0; n < MB; ++n) {
                ar[n] = bir; az[n] = biz; an[n] = bin_;
                hr[n] = bhr; hz[n] = bhz; hn[n] = bhn;
            }
            float4 ra0, rb0;
            ROWLD(ra0, 0)
            ROWLD(rb0, 1)

            // input projection: blocks 0..5 (k = 0..59)
#pragma clang loop unroll(disable)
            for (int kb = 0; kb < 6; ++kb) { BLK10R(kb, ar,az,an) }
            // hidden projection: blocks 6..27 (k = 60..279)
#pragma clang loop unroll(disable)
            for (int kb = 6; kb < 28; ++kb) { BLK10R(kb, hr,hz,hn) }
            // epilogue block 28 (k = 280..289), wraps weight prefetch to block 0
            BLK10W(28, hr,hz,hn)
        }
        __syncthreads();   // B: all waves done reading s_s

        // thread-local gate combine -> new h; publish to LDS + tup
        if (act) {
#pragma unroll
            for (int n = 0; n < MB; ++n) {
                float r  = 1.f / (1.f + expf(-(ar[n] + hr[n])));
                float z  = 1.f / (1.f + expf(-(az[n] + hz[n])));
                float nn = tanhf(an[n] + r * hn[n]);
                float hold = s_s[DIN + tid][n];
                float hnew = (1.f - z) * nn + z * hold;
                s_s[DIN + tid][n] = hnew;
                atomicAdd(&tup[((long)(n0 + n) * SEQ + tt) * HID + tid], hnew);
            }
        }
    }
}

// ---------------- word-level attention ----------------
__global__ __launch_bounds__(256) void k_wordattn(
    const float* __restrict__ tup, const float* __restrict__ attw,
    const float* __restrict__ sen_a, const float* __restrict__ sen_r,
    float* __restrict__ repre, float* __restrict__ sbuf) {
    const int n = blockIdx.x, tid = threadIdx.x;
    __shared__ float tl[SEQ * HID];   // 64400 B
    __shared__ float sc[SEQ];
    __shared__ float red[4];
    for (int i = tid; i < SEQ * HID; i += 256) tl[i] = tup[(long)n * SEQ * HID + i];
    __syncthreads();
    if (tid < SEQ) {
        float s = 0.f;
        for (int h = 0; h < HID; ++h) s += tanhf(tl[tid * HID + h]) * attw[h];
        sc[tid] = s;
    }
    __syncthreads();
    if (tid == 0) {
        float m = sc[0];
        for (int t = 1; t < SEQ; ++t) m = fmaxf(m, sc[t]);
        float ssum = 0.f;
        for (int t = 0; t < SEQ; ++t) { float e = expf(sc[t] - m); sc[t] = e; ssum += e; }
        float inv = 1.f / ssum;
        for (int t = 0; t < SEQ; ++t) sc[t] *= inv;
    }
    __syncthreads();
    float part = 0.f;
    if (tid < HID) {
        float r = 0.f;
        for (int t = 0; t < SEQ; ++t) r = fmaf(sc[t], tl[t * HID + tid], r);
        float rep = tanhf(r);
        repre[(long)n * HID + tid] = rep;
        part = rep * sen_a[tid] * sen_r[tid];
    }
    for (int off = 32; off; off >>= 1) part += __shfl_down(part, off, 64);
    if ((tid & 63) == 0) red[tid >> 6] = part;
    __syncthreads();
    if (tid == 0) sbuf[n] = red[0] + red[1] + red[2] + red[3];
}

// ---------------- bag attention + logits + loss + prob + acc ----------------
__global__ __launch_bounds__(256) void k_bag(
    const float* __restrict__ repre, const float* __restrict__ sbuf,
    const float* __restrict__ rel, const float* __restrict__ sen_d,
    const float* __restrict__ y, float* __restrict__ out, float* __restrict__ bagloss) {
    const int b = blockIdx.x, tid = threadIdx.x;
    __shared__ float al[BAGSZ];
    __shared__ float ss[HID];
    __shared__ float lg[NREL];
    if (tid == 0) {
        float m = -1e30f;
        for (int i = 0; i < BAGSZ; ++i) m = fmaxf(m, sbuf[b * BAGSZ + i]);
        float s = 0.f;
        for (int i = 0; i < BAGSZ; ++i) { float e = expf(sbuf[b * BAGSZ + i] - m); al[i] = e; s += e; }
        float inv = 1.f / s;
        for (int i = 0; i < BAGSZ; ++i) al[i] *= inv;
    }
    __syncthreads();
    if (tid < HID) {
        float acc = 0.f;
        for (int i = 0; i < BAGSZ; ++i)
            acc = fmaf(al[i], repre[(long)(b * BAGSZ + i) * HID + tid], acc);
        ss[tid] = acc;
    }
    __syncthreads();
    if (tid < NREL) {
        float acc = sen_d[tid];
        for (int h = 0; h < HID; ++h) acc = fmaf(ss[h], rel[tid * HID + h], acc);
        lg[tid] = acc;
    }
    __syncthreads();
    if (tid == 0) {
        float m = -1e30f; int am = 0;
        for (int r = 0; r < NREL; ++r) if (lg[r] > m) { m = lg[r]; am = r; }
        float s = 0.f;
        for (int r = 0; r < NREL; ++r) s += expf(lg[r] - m);
        float inv = 1.f / s;
        float ym = -1e30f; int ay = 0;
        for (int r = 0; r < NREL; ++r) { float yy = y[b * NREL + r]; if (yy > ym) { ym = yy; ay = r; } }
        out[1 + b] = (am == ay) ? 1.f : 0.f;
        float loss = 0.f;
        for (int r = 0; r < NREL; ++r) {
            float l = lg[r], yy = y[b * NREL + r];
            loss += fmaxf(l, 0.f) - l * yy + log1pf(expf(-fabsf(l)));
            out[1 + NBAG + b * NREL + r] = expf(l - m) * inv;
        }
        bagloss[b] = loss / NREL;
    }
}

__global__ void k_final(const float* __restrict__ bagloss, float* __restrict__ out) {
    if (blockIdx.x == 0 && threadIdx.x == 0) {
        float s = 0.f;
        for (int i = 0; i < NBAG; ++i) s += bagloss[i];
        out[0] = s;
    }
}

// ---------------- host launcher ----------------
extern "C" void kernel_launch(void* const* d_in, const int* in_sizes, int n_in,
                              void* d_out, int out_size, void* d_ws, size_t ws_size,
                              hipStream_t stream) {
    const int*   sent   = (const int*)d_in[0];
    const int*   pos1   = (const int*)d_in[1];
    const int*   pos2   = (const int*)d_in[2];
    // d_in[3] = total_shape (bag layout is fixed: 64 bags x 32)
    const float* ybatch = (const float*)d_in[4];
    const float* wemb   = (const float*)d_in[5];
    const float* p1tab  = (const float*)d_in[6];
    const float* p2tab  = (const float*)d_in[7];
    const float* Wih_f  = (const float*)d_in[8];
    const float* Whh_f  = (const float*)d_in[9];
    const float* bih_f  = (const float*)d_in[10];
    const float* bhh_f  = (const float*)d_in[11];
    const float* Wih_b  = (const float*)d_in[12];
    const float* Whh_b  = (const float*)d_in[13];
    const float* bih_b  = (const float*)d_in[14];
    const float* bhh_b  = (const float*)d_in[15];
    const float* attw   = (const float*)d_in[16];
    const float* sen_a  = (const float*)d_in[17];
    const float* sen_r  = (const float*)d_in[18];
    const float* rel    = (const float*)d_in[19];
    const float* sen_d  = (const float*)d_in[20];
    float* out = (float*)d_out;

    float* ws = (float*)d_ws;
    size_t off = 0;
    float* emb    = ws + off; off += (size_t)NTOT * SEQ * DIN;   // 8,601,600
    float* wcat_f = ws + off; off += (size_t)SROWS * G3;         // 201,480 (rows 0..59 ih, 60..289 hh)
    float* wcat_b = ws + off; off += (size_t)SROWS * G3;
    float* tup    = ws + off; off += (size_t)NTOT * SEQ * HID;   // 32,998,400
    float* repre  = ws + off; off += (size_t)NTOT * HID;
    float* sbuf   = ws + off; off += (size_t)NTOT;
    float* bagloss= ws + off; off += (size_t)NBAG;

    const long tupN = (long)NTOT * SEQ * HID;
    k_zero<<<(int)((tupN + 255) / 256), 256, 0, stream>>>(tup, tupN);

    const long embN = (long)NTOT * SEQ * DIN;
    k_embed<<<(int)((embN + 255) / 256), 256, 0, stream>>>(sent, pos1, pos2, wemb, p1tab, p2tab, emb);

    // wcat rows 0..59 = Wih^T, rows 60..289 = Whh^T
    k_transpose<<<(G3 * DIN + 255) / 256, 256, 0, stream>>>(Wih_f, wcat_f, G3, DIN);
    k_transpose<<<(G3 * HID + 255) / 256, 256, 0, stream>>>(Whh_f, wcat_f + (size_t)DIN * G3, G3, HID);
    k_transpose<<<(G3 * DIN + 255) / 256, 256, 0, stream>>>(Wih_b, wcat_b, G3, DIN);
    k_transpose<<<(G3 * HID + 255) / 256, 256, 0, stream>>>(Whh_b, wcat_b + (size_t)DIN * G3, G3, HID);

    k_gru<<<(NTOT / MB) * 2, 256, 0, stream>>>(emb,
        wcat_f, bih_f, bhh_f,
        wcat_b, bih_b, bhh_b, tup);

    k_wordattn<<<NTOT, 256, 0, stream>>>(tup, attw, sen_a, sen_r, repre, sbuf);

    k_bag<<<NBAG, 256, 0, stream>>>(repre, sbuf, rel, sen_d, ybatch, out, bagloss);

    k_final<<<1, 64, 0, stream>>>(bagloss, out);
}

// Round 12
// 3374.110 us; speedup vs baseline: 1.1078x; 1.1078x over previous
//
#include <hip/hip_runtime.h>
#include <hip/hip_bf16.h>
#include <math.h>

#define SEQ 70
#define HID 230
#define G3  690
#define EMBD 50
#define DIN 60
#define NTOT 2048
#define NREL 100
#define NBAG 64
#define BAGSZ 32
#define PDIM 5
#define MB 4      // sentences per GRU block -> 1024 blocks = 4 blocks/CU = 4 waves/SIMD
#define KU 10     // k-rows per rolling weight buffer
#define KTOT 290  // DIN + HID unified K stream
#define SROWS 292 // KTOT + 2 pad rows for row-prefetch overrun

// ---------------- prep kernels ----------------

__global__ void k_zero(float* p, long n) {
    long i = (long)blockIdx.x * 256 + threadIdx.x;
    if (i < n) p[i] = 0.f;
}

__global__ void k_embed(const int* __restrict__ sent, const int* __restrict__ p1,
                        const int* __restrict__ p2,  const float* __restrict__ wemb,
                        const float* __restrict__ t1, const float* __restrict__ t2,
                        float* __restrict__ emb) {
    long idx = (long)blockIdx.x * 256 + threadIdx.x;
    long total = (long)NTOT * SEQ * DIN;
    if (idx >= total) return;
    int nt = (int)(idx / DIN);
    int j  = (int)(idx % DIN);
    float v;
    if (j < EMBD)            v = wemb[(long)sent[nt] * EMBD + j];
    else if (j < EMBD + PDIM) v = t1[p1[nt] * PDIM + (j - EMBD)];
    else                      v = t2[p2[nt] * PDIM + (j - EMBD - PDIM)];
    emb[idx] = v;
}

// in[g*K+k] -> out[k*G+g]
__global__ void k_transpose(const float* __restrict__ in, float* __restrict__ out,
                            int G, int K) {
    int idx = blockIdx.x * 256 + threadIdx.x;
    if (idx >= G * K) return;
    int g = idx / K, k = idx % K;
    out[k * G + g] = in[idx];
}

// ---------------- GRU (both directions in one launch) ----------------
// grid = (NTOT/MB)*2 = 1024 blocks of 256 threads -> 4 blocks/CU = 16 waves/CU
// = 4 waves/SIMD. blockIdx.x&1 = direction.
// Thread tid < HID owns gates (tid, HID+tid, 2*HID+tid) -> thread-local combine.
// LAUNCH-BOUNDS CAP LAW (R5-R11 measured): VGPR cap = 256/(arg * blk/256):
// (256,1)->uncapped, (256,2)->128, (512,*)->128, (256,4)->64. The MB=4 kernel
// needs ~95-110 regs (12 acc + 30 weights + rows + bias) -> fits UNDER the
// (256,2) 128-cap with zero spill, while the 1024-block grid gives 4 blocks/CU
// (R11 showed ~40% occupancy even while spilling; here spill is gone).
// Rolling single weight buffer: after FMAs consume w[UE] of block kb, the same
// reg is reloaded with block kb+1 row UE (10-row lead ~ covers L2 latency);
// epilogue wraps prefetch to block 0 (weights t-invariant) -> no per-step stall.
// Old h is re-read from the thread's own LDS row (no hprev regs).
// Unified K stream: wcat rows 0..59 = Wih^T, rows 60..289 = Whh^T.
// s_s rows 0..59 = emb tile (staged per t), rows 60..289 = h state.
// LDS rows depth-2 rotated (ra0/rb0). All register indices compile-time.
// tup must be zeroed beforehand; both directions atomicAdd into it.

#define ROWLD(R0, kk) { R0 = *(const float4*)s_s[kk]; }

#define FMA4(WR,WZ,WN, Q, AR,AZ,AN) \
    AR[0]=fmaf(WR,Q.x,AR[0]); AZ[0]=fmaf(WZ,Q.x,AZ[0]); AN[0]=fmaf(WN,Q.x,AN[0]); \
    AR[1]=fmaf(WR,Q.y,AR[1]); AZ[1]=fmaf(WZ,Q.y,AZ[1]); AN[1]=fmaf(WN,Q.y,AN[1]); \
    AR[2]=fmaf(WR,Q.z,AR[2]); AZ[2]=fmaf(WZ,Q.z,AZ[2]); AN[2]=fmaf(WN,Q.z,AN[2]); \
    AR[3]=fmaf(WR,Q.w,AR[3]); AZ[3]=fmaf(WZ,Q.w,AZ[3]); AN[3]=fmaf(WN,Q.w,AN[3]);

// two k-steps with rolling weight prefetch: consume w[UE] for block KB, then
// reload the SAME slot with block KB+1 row UE (distance 10 rows).
#define U2R(KB, UE, AR,AZ,AN) \
    FMA4(wR[UE],wZ[UE],wN[UE], ra0, AR,AZ,AN); \
    ROWLD(ra0, (KB)*KU+(UE)+2); \
    { int _kk = (((KB)+1)*KU + (UE)) * G3; wR[UE]=pr[_kk]; wZ[UE]=pz[_kk]; wN[UE]=pn[_kk]; } \
    FMA4(wR[UE+1],wZ[UE+1],wN[UE+1], rb0, AR,AZ,AN); \
    ROWLD(rb0, (KB)*KU+(UE)+3); \
    { int _kk = (((KB)+1)*KU + (UE)+1) * G3; wR[UE+1]=pr[_kk]; wZ[UE+1]=pz[_kk]; wN[UE+1]=pn[_kk]; }

// epilogue variant: wrap the weight prefetch to block 0 (for next timestep)
#define U2W(KB, UE, AR,AZ,AN) \
    FMA4(wR[UE],wZ[UE],wN[UE], ra0, AR,AZ,AN); \
    ROWLD(ra0, (KB)*KU+(UE)+2); \
    { int _kk = (UE) * G3; wR[UE]=pr[_kk]; wZ[UE]=pz[_kk]; wN[UE]=pn[_kk]; } \
    FMA4(wR[UE+1],wZ[UE+1],wN[UE+1], rb0, AR,AZ,AN); \
    ROWLD(rb0, (KB)*KU+(UE)+3); \
    { int _kk = ((UE)+1) * G3; wR[UE+1]=pr[_kk]; wZ[UE+1]=pz[_kk]; wN[UE+1]=pn[_kk]; }

#define BLK10R(KB, AR,AZ,AN) \
    U2R(KB, 0, AR,AZ,AN) U2R(KB, 2, AR,AZ,AN) U2R(KB, 4, AR,AZ,AN) \
    U2R(KB, 6, AR,AZ,AN) U2R(KB, 8, AR,AZ,AN)

#define BLK10W(KB, AR,AZ,AN) \
    U2W(KB, 0, AR,AZ,AN) U2W(KB, 2, AR,AZ,AN) U2W(KB, 4, AR,AZ,AN) \
    U2W(KB, 6, AR,AZ,AN) U2W(KB, 8, AR,AZ,AN)

__global__ __launch_bounds__(256, 2) void k_gru(
    const float* __restrict__ emb,
    const float* __restrict__ wcat_f, const float* __restrict__ bih_f, const float* __restrict__ bhh_f,
    const float* __restrict__ wcat_b, const float* __restrict__ bih_b, const float* __restrict__ bhh_b,
    float* __restrict__ tup) {

    const bool rev = blockIdx.x & 1;
    const int  n0  = (blockIdx.x >> 1) * MB;
    const float* wcat = rev ? wcat_b : wcat_f;
    const float* bih  = rev ? bih_b  : bih_f;
    const float* bhh  = rev ? bhh_b  : bhh_f;
    const int tid = threadIdx.x;
    const bool act = tid < HID;

    __shared__ float s_s[SROWS][MB];   // 4672 B: rows 0..59 = e, 60..289 = h

    for (int i = tid; i < SROWS * MB; i += 256) ((float*)s_s)[i] = 0.f;

    float bir = 0.f, biz = 0.f, bin_ = 0.f, bhr = 0.f, bhz = 0.f, bhn = 0.f;
    if (act) {
        bir = bih[tid]; biz = bih[HID + tid]; bin_ = bih[2 * HID + tid];
        bhr = bhh[tid]; bhz = bhh[HID + tid]; bhn = bhh[2 * HID + tid];
    }

    const float* pr = wcat + tid;            // row k at pr[k*G3]
    const float* pz = wcat + HID + tid;
    const float* pn = wcat + 2 * HID + tid;

    // rolling weight buffer: preload block 0 once; steady-state refills happen
    // inside U2R/U2W with 10-row lead. Weights are t-invariant.
    float wR[KU], wZ[KU], wN[KU];
    if (act) {
#pragma unroll
        for (int u = 0; u < KU; ++u) {
            int kk = u * G3; wR[u] = pr[kk]; wZ[u] = pz[kk]; wN[u] = pn[kk];
        }
    }

    __syncthreads();

    for (int t = 0; t < SEQ; ++t) {
        const int tt = rev ? (SEQ - 1 - t) : t;

        // stage emb tile into s_s rows 0..59 (240 elems, 256 threads)
        if (tid < DIN * MB) {
            int n = tid / DIN, k = tid - n * DIN;
            s_s[k][n] = emb[((long)(n0 + n) * SEQ + tt) * DIN + k];
        }
        __syncthreads();   // A: e rows staged, h rows published

        float ar[MB], az[MB], an[MB], hr[MB], hz[MB], hn[MB];
        if (act) {
#pragma unroll
            for (int n = 0; n < MB; ++n) {
                ar[n] = bir; az[n] = biz; an[n] = bin_;
                hr[n] = bhr; hz[n] = bhz; hn[n] = bhn;
            }
            float4 ra0, rb0;
            ROWLD(ra0, 0)
            ROWLD(rb0, 1)

            // input projection: blocks 0..5 (k = 0..59)
#pragma clang loop unroll(disable)
            for (int kb = 0; kb < 6; ++kb) { BLK10R(kb, ar,az,an) }
            // hidden projection: blocks 6..27 (k = 60..279)
#pragma clang loop unroll(disable)
            for (int kb = 6; kb < 28; ++kb) { BLK10R(kb, hr,hz,hn) }
            // epilogue block 28 (k = 280..289), wraps weight prefetch to block 0
            BLK10W(28, hr,hz,hn)
        }
        __syncthreads();   // B: all waves done reading s_s

        // thread-local gate combine -> new h; publish to LDS + tup
        if (act) {
#pragma unroll
            for (int n = 0; n < MB; ++n) {
                float r  = 1.f / (1.f + expf(-(ar[n] + hr[n])));
                float z  = 1.f / (1.f + expf(-(az[n] + hz[n])));
                float nn = tanhf(an[n] + r * hn[n]);
                float hold = s_s[DIN + tid][n];
                float hnew = (1.f - z) * nn + z * hold;
                s_s[DIN + tid][n] = hnew;
                atomicAdd(&tup[((long)(n0 + n) * SEQ + tt) * HID + tid], hnew);
            }
        }
    }
}

// ---------------- word-level attention ----------------
__global__ __launch_bounds__(256) void k_wordattn(
    const float* __restrict__ tup, const float* __restrict__ attw,
    const float* __restrict__ sen_a, const float* __restrict__ sen_r,
    float* __restrict__ repre, float* __restrict__ sbuf) {
    const int n = blockIdx.x, tid = threadIdx.x;
    __shared__ float tl[SEQ * HID];   // 64400 B
    __shared__ float sc[SEQ];
    __shared__ float red[4];
    for (int i = tid; i < SEQ * HID; i += 256) tl[i] = tup[(long)n * SEQ * HID + i];
    __syncthreads();
    if (tid < SEQ) {
        float s = 0.f;
        for (int h = 0; h < HID; ++h) s += tanhf(tl[tid * HID + h]) * attw[h];
        sc[tid] = s;
    }
    __syncthreads();
    if (tid == 0) {
        float m = sc[0];
        for (int t = 1; t < SEQ; ++t) m = fmaxf(m, sc[t]);
        float ssum = 0.f;
        for (int t = 0; t < SEQ; ++t) { float e = expf(sc[t] - m); sc[t] = e; ssum += e; }
        float inv = 1.f / ssum;
        for (int t = 0; t < SEQ; ++t) sc[t] *= inv;
    }
    __syncthreads();
    float part = 0.f;
    if (tid < HID) {
        float r = 0.f;
        for (int t = 0; t < SEQ; ++t) r = fmaf(sc[t], tl[t * HID + tid], r);
        float rep = tanhf(r);
        repre[(long)n * HID + tid] = rep;
        part = rep * sen_a[tid] * sen_r[tid];
    }
    for (int off = 32; off; off >>= 1) part += __shfl_down(part, off, 64);
    if ((tid & 63) == 0) red[tid >> 6] = part;
    __syncthreads();
    if (tid == 0) sbuf[n] = red[0] + red[1] + red[2] + red[3];
}

// ---------------- bag attention + logits + loss + prob + acc ----------------
__global__ __launch_bounds__(256) void k_bag(
    const float* __restrict__ repre, const float* __restrict__ sbuf,
    const float* __restrict__ rel, const float* __restrict__ sen_d,
    const float* __restrict__ y, float* __restrict__ out, float* __restrict__ bagloss) {
    const int b = blockIdx.x, tid = threadIdx.x;
    __shared__ float al[BAGSZ];
    __shared__ float ss[HID];
    __shared__ float lg[NREL];
    if (tid == 0) {
        float m = -1e30f;
        for (int i = 0; i < BAGSZ; ++i) m = fmaxf(m, sbuf[b * BAGSZ + i]);
        float s = 0.f;
        for (int i = 0; i < BAGSZ; ++i) { float e = expf(sbuf[b * BAGSZ + i] - m); al[i] = e; s += e; }
        float inv = 1.f / s;
        for (int i = 0; i < BAGSZ; ++i) al[i] *= inv;
    }
    __syncthreads();
    if (tid < HID) {
        float acc = 0.f;
        for (int i = 0; i < BAGSZ; ++i)
            acc = fmaf(al[i], repre[(long)(b * BAGSZ + i) * HID + tid], acc);
        ss[tid] = acc;
    }
    __syncthreads();
    if (tid < NREL) {
        float acc = sen_d[tid];
        for (int h = 0; h < HID; ++h) acc = fmaf(ss[h], rel[tid * HID + h], acc);
        lg[tid] = acc;
    }
    __syncthreads();
    if (tid == 0) {
        float m = -1e30f; int am = 0;
        for (int r = 0; r < NREL; ++r) if (lg[r] > m) { m = lg[r]; am = r; }
        float s = 0.f;
        for (int r = 0; r < NREL; ++r) s += expf(lg[r] - m);
        float inv = 1.f / s;
        float ym = -1e30f; int ay = 0;
        for (int r = 0; r < NREL; ++r) { float yy = y[b * NREL + r]; if (yy > ym) { ym = yy; ay = r; } }
        out[1 + b] = (am == ay) ? 1.f : 0.f;
        float loss = 0.f;
        for (int r = 0; r < NREL; ++r) {
            float l = lg[r], yy = y[b * NREL + r];
            loss += fmaxf(l, 0.f) - l * yy + log1pf(expf(-fabsf(l)));
            out[1 + NBAG + b * NREL + r] = expf(l - m) * inv;
        }
        bagloss[b] = loss / NREL;
    }
}

__global__ void k_final(const float* __restrict__ bagloss, float* __restrict__ out) {
    if (blockIdx.x == 0 && threadIdx.x == 0) {
        float s = 0.f;
        for (int i = 0; i < NBAG; ++i) s += bagloss[i];
        out[0] = s;
    }
}

// ---------------- host launcher ----------------
extern "C" void kernel_launch(void* const* d_in, const int* in_sizes, int n_in,
                              void* d_out, int out_size, void* d_ws, size_t ws_size,
                              hipStream_t stream) {
    const int*   sent   = (const int*)d_in[0];
    const int*   pos1   = (const int*)d_in[1];
    const int*   pos2   = (const int*)d_in[2];
    // d_in[3] = total_shape (bag layout is fixed: 64 bags x 32)
    const float* ybatch = (const float*)d_in[4];
    const float* wemb   = (const float*)d_in[5];
    const float* p1tab  = (const float*)d_in[6];
    const float* p2tab  = (const float*)d_in[7];
    const float* Wih_f  = (const float*)d_in[8];
    const float* Whh_f  = (const float*)d_in[9];
    const float* bih_f  = (const float*)d_in[10];
    const float* bhh_f  = (const float*)d_in[11];
    const float* Wih_b  = (const float*)d_in[12];
    const float* Whh_b  = (const float*)d_in[13];
    const float* bih_b  = (const float*)d_in[14];
    const float* bhh_b  = (const float*)d_in[15];
    const float* attw   = (const float*)d_in[16];
    const float* sen_a  = (const float*)d_in[17];
    const float* sen_r  = (const float*)d_in[18];
    const float* rel    = (const float*)d_in[19];
    const float* sen_d  = (const float*)d_in[20];
    float* out = (float*)d_out;

    float* ws = (float*)d_ws;
    size_t off = 0;
    float* emb    = ws + off; off += (size_t)NTOT * SEQ * DIN;   // 8,601,600
    float* wcat_f = ws + off; off += (size_t)SROWS * G3;         // 201,480 (rows 0..59 ih, 60..289 hh)
    float* wcat_b = ws + off; off += (size_t)SROWS * G3;
    float* tup    = ws + off; off += (size_t)NTOT * SEQ * HID;   // 32,998,400
    float* repre  = ws + off; off += (size_t)NTOT * HID;
    float* sbuf   = ws + off; off += (size_t)NTOT;
    float* bagloss= ws + off; off += (size_t)NBAG;

    const long tupN = (long)NTOT * SEQ * HID;
    k_zero<<<(int)((tupN + 255) / 256), 256, 0, stream>>>(tup, tupN);

    const long embN = (long)NTOT * SEQ * DIN;
    k_embed<<<(int)((embN + 255) / 256), 256, 0, stream>>>(sent, pos1, pos2, wemb, p1tab, p2tab, emb);

    // wcat rows 0..59 = Wih^T, rows 60..289 = Whh^T
    k_transpose<<<(G3 * DIN + 255) / 256, 256, 0, stream>>>(Wih_f, wcat_f, G3, DIN);
    k_transpose<<<(G3 * HID + 255) / 256, 256, 0, stream>>>(Whh_f, wcat_f + (size_t)DIN * G3, G3, HID);
    k_transpose<<<(G3 * DIN + 255) / 256, 256, 0, stream>>>(Wih_b, wcat_b, G3, DIN);
    k_transpose<<<(G3 * HID + 255) / 256, 256, 0, stream>>>(Whh_b, wcat_b + (size_t)DIN * G3, G3, HID);

    k_gru<<<(NTOT / MB) * 2, 256, 0, stream>>>(emb,
        wcat_f, bih_f, bhh_f,
        wcat_b, bih_b, bhh_b, tup);

    k_wordattn<<<NTOT, 256, 0, stream>>>(tup, attw, sen_a, sen_r, repre, sbuf);

    k_bag<<<NBAG, 256, 0, stream>>>(repre, sbuf, rel, sen_d, ybatch, out, bagloss);

    k_final<<<1, 64, 0, stream>>>(bagloss, out);
}

// Round 13
// 3131.230 us; speedup vs baseline: 1.1938x; 1.0776x over previous
//
#include <hip/hip_runtime.h>
#include <hip/hip_bf16.h>
#include <math.h>

#define SEQ 70
#define HID 230
#define G3  690
#define EMBD 50
#define DIN 60
#define NTOT 2048
#define NREL 100
#define NBAG 64
#define BAGSZ 32
#define PDIM 5
#define MB 4      // sentences per GRU block -> 1024 blocks = 4 blocks/CU = 4 waves/SIMD
#define KU 5      // k-rows per rolling weight buffer (divides 60 and 230)
#define KTOT 290  // DIN + HID unified K stream
#define SROWS 292 // KTOT + 2 pad rows for row-prefetch overrun

// ---------------- prep kernels ----------------

__global__ void k_zero(float* p, long n) {
    long i = (long)blockIdx.x * 256 + threadIdx.x;
    if (i < n) p[i] = 0.f;
}

__global__ void k_embed(const int* __restrict__ sent, const int* __restrict__ p1,
                        const int* __restrict__ p2,  const float* __restrict__ wemb,
                        const float* __restrict__ t1, const float* __restrict__ t2,
                        float* __restrict__ emb) {
    long idx = (long)blockIdx.x * 256 + threadIdx.x;
    long total = (long)NTOT * SEQ * DIN;
    if (idx >= total) return;
    int nt = (int)(idx / DIN);
    int j  = (int)(idx % DIN);
    float v;
    if (j < EMBD)            v = wemb[(long)sent[nt] * EMBD + j];
    else if (j < EMBD + PDIM) v = t1[p1[nt] * PDIM + (j - EMBD)];
    else                      v = t2[p2[nt] * PDIM + (j - EMBD - PDIM)];
    emb[idx] = v;
}

// in[g*K+k] -> out[k*G+g]
__global__ void k_transpose(const float* __restrict__ in, float* __restrict__ out,
                            int G, int K) {
    int idx = blockIdx.x * 256 + threadIdx.x;
    if (idx >= G * K) return;
    int g = idx / K, k = idx % K;
    out[k * G + g] = in[idx];
}

// ---------------- GRU (both directions in one launch) ----------------
// grid = (NTOT/MB)*2 = 1024 blocks of 256 threads. blockIdx.x&1 = direction.
// Thread tid < HID owns gates (tid, HID+tid, 2*HID+tid) -> thread-local combine.
// DESCRIPTOR LAW (R5-R12 measured): launch_bounds(256,N) reserves 256/N regs
// per wave in the kernel descriptor REGARDLESS of actual VGPR_Count; resident
// waves/SIMD == N exactly. Actual usage only determines spill. So 4 waves/SIMD
// without spill requires a <=64-reg kernel. Register plan (~59):
//   acc 24 (6 gates x MB=4) + rolling weights KU=5 (15) + row reg (4)
//   + bias 6 + ONE weight base pointer (z/n gates via imm-folded offsets
//   +HID*4=920B / +2*HID*4=1840B, both < 4096B imm range) + misc.
// Depth-1 LDS row (no rotation): ~100cy/row exposed per wave, but 4 waves/SIMD
// (duty ~35% x 4 = saturated) cover it — TLP replaces the reg-hungry pipeline.
// Rolling weights: after FMAs consume w[u] of block kb, the same slot reloads
// block kb+1 row u (5-row lead; wall-time stretch x4 from TLP covers L2).
// Epilogue block 57 wraps the prefetch to block 0 (weights t-invariant).
// Unified K stream: wcat rows 0..59 = Wih^T, rows 60..289 = Whh^T.
// s_s rows 0..59 = emb tile (staged per t), rows 60..289 = h state.
// tup must be zeroed beforehand; both directions atomicAdd into it.

#define ROWLD(kk) { ra0 = *(const float4*)s_s[kk]; }

#define FMA4(WR,WZ,WN, AR,AZ,AN) \
    AR[0]=fmaf(WR,ra0.x,AR[0]); AZ[0]=fmaf(WZ,ra0.x,AZ[0]); AN[0]=fmaf(WN,ra0.x,AN[0]); \
    AR[1]=fmaf(WR,ra0.y,AR[1]); AZ[1]=fmaf(WZ,ra0.y,AZ[1]); AN[1]=fmaf(WN,ra0.y,AN[1]); \
    AR[2]=fmaf(WR,ra0.z,AR[2]); AZ[2]=fmaf(WZ,ra0.z,AZ[2]); AN[2]=fmaf(WN,ra0.z,AN[2]); \
    AR[3]=fmaf(WR,ra0.w,AR[3]); AZ[3]=fmaf(WZ,ra0.w,AZ[3]); AN[3]=fmaf(WN,ra0.w,AN[3]);

// one k-step: FMA row k (in ra0), load row k+1, reload weight slot from kb+1
#define U1R(KB, UE, AR,AZ,AN) \
    FMA4(wR[UE],wZ[UE],wN[UE], AR,AZ,AN); \
    ROWLD((KB)*KU+(UE)+1); \
    { int _kk = (((KB)+1)*KU + (UE)) * G3; \
      wR[UE]=pw[_kk]; wZ[UE]=pw[_kk+HID]; wN[UE]=pw[_kk+2*HID]; }

// epilogue variant: wrap the weight prefetch to block 0 (for next timestep)
#define U1W(KB, UE, AR,AZ,AN) \
    FMA4(wR[UE],wZ[UE],wN[UE], AR,AZ,AN); \
    ROWLD((KB)*KU+(UE)+1); \
    { int _kk = (UE) * G3; \
      wR[UE]=pw[_kk]; wZ[UE]=pw[_kk+HID]; wN[UE]=pw[_kk+2*HID]; }

#define BLK5R(KB, AR,AZ,AN) \
    U1R(KB, 0, AR,AZ,AN) U1R(KB, 1, AR,AZ,AN) U1R(KB, 2, AR,AZ,AN) \
    U1R(KB, 3, AR,AZ,AN) U1R(KB, 4, AR,AZ,AN)

#define BLK5W(KB, AR,AZ,AN) \
    U1W(KB, 0, AR,AZ,AN) U1W(KB, 1, AR,AZ,AN) U1W(KB, 2, AR,AZ,AN) \
    U1W(KB, 3, AR,AZ,AN) U1W(KB, 4, AR,AZ,AN)

__global__ __launch_bounds__(256, 4) void k_gru(
    const float* __restrict__ emb,
    const float* __restrict__ wcat_f, const float* __restrict__ bih_f, const float* __restrict__ bhh_f,
    const float* __restrict__ wcat_b, const float* __restrict__ bih_b, const float* __restrict__ bhh_b,
    float* __restrict__ tup) {

    const bool rev = blockIdx.x & 1;
    const int  n0  = (blockIdx.x >> 1) * MB;
    const float* wcat = rev ? wcat_b : wcat_f;
    const float* bih  = rev ? bih_b  : bih_f;
    const float* bhh  = rev ? bhh_b  : bhh_f;
    const int tid = threadIdx.x;
    const bool act = tid < HID;

    __shared__ float s_s[SROWS][MB];   // 4672 B: rows 0..59 = e, 60..289 = h

    for (int i = tid; i < SROWS * MB; i += 256) ((float*)s_s)[i] = 0.f;

    float bir = 0.f, biz = 0.f, bin_ = 0.f, bhr = 0.f, bhz = 0.f, bhn = 0.f;
    if (act) {
        bir = bih[tid]; biz = bih[HID + tid]; bin_ = bih[2 * HID + tid];
        bhr = bhh[tid]; bhz = bhh[HID + tid]; bhn = bhh[2 * HID + tid];
    }

    const float* pw = wcat + tid;  // row k: pw[k*G3] (r), +HID (z), +2*HID (n)

    // rolling weight buffer: preload block 0 once; steady-state refills happen
    // inside U1R/U1W with 5-row lead. Weights are t-invariant.
    float wR[KU], wZ[KU], wN[KU];
    if (act) {
#pragma unroll
        for (int u = 0; u < KU; ++u) {
            int kk = u * G3; wR[u] = pw[kk]; wZ[u] = pw[kk + HID]; wN[u] = pw[kk + 2 * HID];
        }
    }

    __syncthreads();

    for (int t = 0; t < SEQ; ++t) {
        const int tt = rev ? (SEQ - 1 - t) : t;

        // stage emb tile into s_s rows 0..59 (240 elems, 256 threads)
        if (tid < DIN * MB) {
            int n = tid / DIN, k = tid - n * DIN;
            s_s[k][n] = emb[((long)(n0 + n) * SEQ + tt) * DIN + k];
        }
        __syncthreads();   // A: e rows staged, h rows published

        float ar[MB], az[MB], an[MB], hr[MB], hz[MB], hn[MB];
        if (act) {
#pragma unroll
            for (int n = 0; n < MB; ++n) {
                ar[n] = bir; az[n] = biz; an[n] = bin_;
                hr[n] = bhr; hz[n] = bhz; hn[n] = bhn;
            }
            float4 ra0;
            ROWLD(0)

            // input projection: blocks 0..11 (k = 0..59)
#pragma clang loop unroll(disable)
            for (int kb = 0; kb < 12; ++kb) { BLK5R(kb, ar,az,an) }
            // hidden projection: blocks 12..56 (k = 60..284)
#pragma clang loop unroll(disable)
            for (int kb = 12; kb < 57; ++kb) { BLK5R(kb, hr,hz,hn) }
            // epilogue block 57 (k = 285..289), wraps weight prefetch to block 0
            BLK5W(57, hr,hz,hn)
        }
        __syncthreads();   // B: all waves done reading s_s

        // thread-local gate combine -> new h; publish to LDS + tup
        if (act) {
#pragma unroll
            for (int n = 0; n < MB; ++n) {
                float r  = 1.f / (1.f + expf(-(ar[n] + hr[n])));
                float z  = 1.f / (1.f + expf(-(az[n] + hz[n])));
                float nn = tanhf(an[n] + r * hn[n]);
                float hold = s_s[DIN + tid][n];
                float hnew = (1.f - z) * nn + z * hold;
                s_s[DIN + tid][n] = hnew;
                atomicAdd(&tup[((long)(n0 + n) * SEQ + tt) * HID + tid], hnew);
            }
        }
    }
}

// ---------------- word-level attention ----------------
__global__ __launch_bounds__(256) void k_wordattn(
    const float* __restrict__ tup, const float* __restrict__ attw,
    const float* __restrict__ sen_a, const float* __restrict__ sen_r,
    float* __restrict__ repre, float* __restrict__ sbuf) {
    const int n = blockIdx.x, tid = threadIdx.x;
    __shared__ float tl[SEQ * HID];   // 64400 B
    __shared__ float sc[SEQ];
    __shared__ float red[4];
    for (int i = tid; i < SEQ * HID; i += 256) tl[i] = tup[(long)n * SEQ * HID + i];
    __syncthreads();
    if (tid < SEQ) {
        float s = 0.f;
        for (int h = 0; h < HID; ++h) s += tanhf(tl[tid * HID + h]) * attw[h];
        sc[tid] = s;
    }
    __syncthreads();
    if (tid == 0) {
        float m = sc[0];
        for (int t = 1; t < SEQ; ++t) m = fmaxf(m, sc[t]);
        float ssum = 0.f;
        for (int t = 0; t < SEQ; ++t) { float e = expf(sc[t] - m); sc[t] = e; ssum += e; }
        float inv = 1.f / ssum;
        for (int t = 0; t < SEQ; ++t) sc[t] *= inv;
    }
    __syncthreads();
    float part = 0.f;
    if (tid < HID) {
        float r = 0.f;
        for (int t = 0; t < SEQ; ++t) r = fmaf(sc[t], tl[t * HID + tid], r);
        float rep = tanhf(r);
        repre[(long)n * HID + tid] = rep;
        part = rep * sen_a[tid] * sen_r[tid];
    }
    for (int off = 32; off; off >>= 1) part += __shfl_down(part, off, 64);
    if ((tid & 63) == 0) red[tid >> 6] = part;
    __syncthreads();
    if (tid == 0) sbuf[n] = red[0] + red[1] + red[2] + red[3];
}

// ---------------- bag attention + logits + loss + prob + acc ----------------
__global__ __launch_bounds__(256) void k_bag(
    const float* __restrict__ repre, const float* __restrict__ sbuf,
    const float* __restrict__ rel, const float* __restrict__ sen_d,
    const float* __restrict__ y, float* __restrict__ out, float* __restrict__ bagloss) {
    const int b = blockIdx.x, tid = threadIdx.x;
    __shared__ float al[BAGSZ];
    __shared__ float ss[HID];
    __shared__ float lg[NREL];
    if (tid == 0) {
        float m = -1e30f;
        for (int i = 0; i < BAGSZ; ++i) m = fmaxf(m, sbuf[b * BAGSZ + i]);
        float s = 0.f;
        for (int i = 0; i < BAGSZ; ++i) { float e = expf(sbuf[b * BAGSZ + i] - m); al[i] = e; s += e; }
        float inv = 1.f / s;
        for (int i = 0; i < BAGSZ; ++i) al[i] *= inv;
    }
    __syncthreads();
    if (tid < HID) {
        float acc = 0.f;
        for (int i = 0; i < BAGSZ; ++i)
            acc = fmaf(al[i], repre[(long)(b * BAGSZ + i) * HID + tid], acc);
        ss[tid] = acc;
    }
    __syncthreads();
    if (tid < NREL) {
        float acc = sen_d[tid];
        for (int h = 0; h < HID; ++h) acc = fmaf(ss[h], rel[tid * HID + h], acc);
        lg[tid] = acc;
    }
    __syncthreads();
    if (tid == 0) {
        float m = -1e30f; int am = 0;
        for (int r = 0; r < NREL; ++r) if (lg[r] > m) { m = lg[r]; am = r; }
        float s = 0.f;
        for (int r = 0; r < NREL; ++r) s += expf(lg[r] - m);
        float inv = 1.f / s;
        float ym = -1e30f; int ay = 0;
        for (int r = 0; r < NREL; ++r) { float yy = y[b * NREL + r]; if (yy > ym) { ym = yy; ay = r; } }
        out[1 + b] = (am == ay) ? 1.f : 0.f;
        float loss = 0.f;
        for (int r = 0; r < NREL; ++r) {
            float l = lg[r], yy = y[b * NREL + r];
            loss += fmaxf(l, 0.f) - l * yy + log1pf(expf(-fabsf(l)));
            out[1 + NBAG + b * NREL + r] = expf(l - m) * inv;
        }
        bagloss[b] = loss / NREL;
    }
}

__global__ void k_final(const float* __restrict__ bagloss, float* __restrict__ out) {
    if (blockIdx.x == 0 && threadIdx.x == 0) {
        float s = 0.f;
        for (int i = 0; i < NBAG; ++i) s += bagloss[i];
        out[0] = s;
    }
}

// ---------------- host launcher ----------------
extern "C" void kernel_launch(void* const* d_in, const int* in_sizes, int n_in,
                              void* d_out, int out_size, void* d_ws, size_t ws_size,
                              hipStream_t stream) {
    const int*   sent   = (const int*)d_in[0];
    const int*   pos1   = (const int*)d_in[1];
    const int*   pos2   = (const int*)d_in[2];
    // d_in[3] = total_shape (bag layout is fixed: 64 bags x 32)
    const float* ybatch = (const float*)d_in[4];
    const float* wemb   = (const float*)d_in[5];
    const float* p1tab  = (const float*)d_in[6];
    const float* p2tab  = (const float*)d_in[7];
    const float* Wih_f  = (const float*)d_in[8];
    const float* Whh_f  = (const float*)d_in[9];
    const float* bih_f  = (const float*)d_in[10];
    const float* bhh_f  = (const float*)d_in[11];
    const float* Wih_b  = (const float*)d_in[12];
    const float* Whh_b  = (const float*)d_in[13];
    const float* bih_b  = (const float*)d_in[14];
    const float* bhh_b  = (const float*)d_in[15];
    const float* attw   = (const float*)d_in[16];
    const float* sen_a  = (const float*)d_in[17];
    const float* sen_r  = (const float*)d_in[18];
    const float* rel    = (const float*)d_in[19];
    const float* sen_d  = (const float*)d_in[20];
    float* out = (float*)d_out;

    float* ws = (float*)d_ws;
    size_t off = 0;
    float* emb    = ws + off; off += (size_t)NTOT * SEQ * DIN;   // 8,601,600
    float* wcat_f = ws + off; off += (size_t)SROWS * G3;         // 201,480 (rows 0..59 ih, 60..289 hh)
    float* wcat_b = ws + off; off += (size_t)SROWS * G3;
    float* tup    = ws + off; off += (size_t)NTOT * SEQ * HID;   // 32,998,400
    float* repre  = ws + off; off += (size_t)NTOT * HID;
    float* sbuf   = ws + off; off += (size_t)NTOT;
    float* bagloss= ws + off; off += (size_t)NBAG;

    const long tupN = (long)NTOT * SEQ * HID;
    k_zero<<<(int)((tupN + 255) / 256), 256, 0, stream>>>(tup, tupN);

    const long embN = (long)NTOT * SEQ * DIN;
    k_embed<<<(int)((embN + 255) / 256), 256, 0, stream>>>(sent, pos1, pos2, wemb, p1tab, p2tab, emb);

    // wcat rows 0..59 = Wih^T, rows 60..289 = Whh^T
    k_transpose<<<(G3 * DIN + 255) / 256, 256, 0, stream>>>(Wih_f, wcat_f, G3, DIN);
    k_transpose<<<(G3 * HID + 255) / 256, 256, 0, stream>>>(Whh_f, wcat_f + (size_t)DIN * G3, G3, HID);
    k_transpose<<<(G3 * DIN + 255) / 256, 256, 0, stream>>>(Wih_b, wcat_b, G3, DIN);
    k_transpose<<<(G3 * HID + 255) / 256, 256, 0, stream>>>(Whh_b, wcat_b + (size_t)DIN * G3, G3, HID);

    k_gru<<<(NTOT / MB) * 2, 256, 0, stream>>>(emb,
        wcat_f, bih_f, bhh_f,
        wcat_b, bih_b, bhh_b, tup);

    k_wordattn<<<NTOT, 256, 0, stream>>>(tup, attw, sen_a, sen_r, repre, sbuf);

    k_bag<<<NBAG, 256, 0, stream>>>(repre, sbuf, rel, sen_d, ybatch, out, bagloss);

    k_final<<<1, 64, 0, stream>>>(bagloss, out);
}

// Round 15
// 3111.185 us; speedup vs baseline: 1.2015x; 1.0064x over previous
//
#include <hip/hip_runtime.h>
#include <hip/hip_bf16.h>
#include <math.h>

#define SEQ 70
#define HID 230
#define G3  690
#define EMBD 50
#define DIN 60
#define NTOT 2048
#define NREL 100
#define NBAG 64
#define BAGSZ 32
#define PDIM 5
#define MB 8      // sentences per GRU block -> 512 blocks, 2 blocks/CU
#define KU 8      // rolling weight slots; slot = k mod 8
#define SROWS 316 // LDS rows: 0..59 e, 60..315 h (230 real + pad for slices)
#define WROWS 298 // wcat rows: 0..289 real, 290..297 dup of logical (row&7)

// ---------------- prep kernels ----------------

__global__ void k_zero(float* p, long n) {
    long i = (long)blockIdx.x * 256 + threadIdx.x;
    if (i < n) p[i] = 0.f;
}

__global__ void k_embed(const int* __restrict__ sent, const int* __restrict__ p1,
                        const int* __restrict__ p2,  const float* __restrict__ wemb,
                        const float* __restrict__ t1, const float* __restrict__ t2,
                        float* __restrict__ emb) {
    long idx = (long)blockIdx.x * 256 + threadIdx.x;
    long total = (long)NTOT * SEQ * DIN;
    if (idx >= total) return;
    int nt = (int)(idx / DIN);
    int j  = (int)(idx % DIN);
    float v;
    if (j < EMBD)            v = wemb[(long)sent[nt] * EMBD + j];
    else if (j < EMBD + PDIM) v = t1[p1[nt] * PDIM + (j - EMBD)];
    else                      v = t2[p2[nt] * PDIM + (j - EMBD - PDIM)];
    emb[idx] = v;
}

// in[g*K+k] -> out[k*G+g]
__global__ void k_transpose(const float* __restrict__ in, float* __restrict__ out,
                            int G, int K) {
    int idx = blockIdx.x * 256 + threadIdx.x;
    if (idx >= G * K) return;
    int g = idx / K, k = idx % K;
    out[k * G + g] = in[idx];
}

// duplicate rows 290..297 of wcat from logical rows (row & 7) so the rolling
// weight prefetch (row k+8) wraps without breaking the slot == k mod 8 law
__global__ void k_dupe(float* __restrict__ w) {
    int idx = blockIdx.x * 256 + threadIdx.x;
    if (idx >= 8 * G3) return;
    int i = idx / G3, g = idx % G3;
    w[(290 + i) * G3 + g] = w[((290 + i) & 7) * G3 + g];
}

// ---------------- GRU (both directions in one launch) ----------------
// grid = (NTOT/MB)*2 = 512 blocks of 256 threads, (256,2) -> 2 blocks/CU.
// Thread tid < HID owns gates (tid, HID+tid, 2*HID+tid) -> thread-local combine.
//
// KEY CHANGE vs R9-R13 (which were limited by wall ~= base + LDS + L2, with
// LDS-uniform-broadcast reads an invariant 1.5 ms total): the h-broadcast no
// longer goes through the LDS pipe. Each wave slurps the WHOLE h vector into
// per-lane register slices once per step (lane L, slice s holds h[60+64s+L],
// 4 slices x 8 floats = 32 VGPRs; slurp = 8 per-lane-distinct ds_read_b128
// per wave instead of 460 uniform reads). Per k, h[k][0..7] is broadcast via
// v_readlane_b32 (VALU->SGPR, lane index uniform) and feeds the FMA as the
// single allowed SGPR operand. LDS pipe: 46k -> ~2k cy/CU-step.
// e-part (rows 0..59, restaged per t) keeps the cheap LDS-uniform path.
// Rolling weights: slot u holds row r with r == u (mod 8); consume slot at k,
// reload row k+8 into the same slot. wcat rows 290..297 duplicate logical
// (row&7) so the wrap to the next timestep needs no special casing.
// Accumulators: ar/az/an over k=0..59 (bias bih), hr/hz/hn over k=60..289
// (bias bhh), both strictly k-ascending -> bitwise-identical to reference.
// tup must be zeroed beforehand; both directions atomicAdd into it.

#define RL(v, ln) __int_as_float(__builtin_amdgcn_readlane(__float_as_int(v), (ln)))

#define FMA24(WRv,WZv,WNv, B0,B1,B2,B3,B4,B5,B6,B7, AR,AZ,AN) \
    AR[0]=fmaf(WRv,B0,AR[0]); AZ[0]=fmaf(WZv,B0,AZ[0]); AN[0]=fmaf(WNv,B0,AN[0]); \
    AR[1]=fmaf(WRv,B1,AR[1]); AZ[1]=fmaf(WZv,B1,AZ[1]); AN[1]=fmaf(WNv,B1,AN[1]); \
    AR[2]=fmaf(WRv,B2,AR[2]); AZ[2]=fmaf(WZv,B2,AZ[2]); AN[2]=fmaf(WNv,B2,AN[2]); \
    AR[3]=fmaf(WRv,B3,AR[3]); AZ[3]=fmaf(WZv,B3,AZ[3]); AN[3]=fmaf(WNv,B3,AN[3]); \
    AR[4]=fmaf(WRv,B4,AR[4]); AZ[4]=fmaf(WZv,B4,AZ[4]); AN[4]=fmaf(WNv,B4,AN[4]); \
    AR[5]=fmaf(WRv,B5,AR[5]); AZ[5]=fmaf(WZv,B5,AZ[5]); AN[5]=fmaf(WNv,B5,AN[5]); \
    AR[6]=fmaf(WRv,B6,AR[6]); AZ[6]=fmaf(WZv,B6,AZ[6]); AN[6]=fmaf(WNv,B6,AN[6]); \
    AR[7]=fmaf(WRv,B7,AR[7]); AZ[7]=fmaf(WZv,B7,AZ[7]); AN[7]=fmaf(WNv,B7,AN[7]);

// e-step at k = eb8+U (slot U): FMA from LDS row buffer, prefetch row k+1,
// reload weight slot U from row k+8
#define ESTEP(U) \
    FMA24(wR[U],wZ[U],wN[U], ra0.x,ra0.y,ra0.z,ra0.w, ra1.x,ra1.y,ra1.z,ra1.w, ar,az,an); \
    { int kk = eb8 + (U); \
      ra0 = *(const float4*)&s_s[kk+1][0]; ra1 = *(const float4*)&s_s[kk+1][4]; \
      int ro = (kk + 8) * G3; wR[U]=pw[ro]; wZ[U]=pw[ro+HID]; wN[U]=pw[ro+2*HID]; }

// h-step at k = 60+64*S+jb8+U (slot (4+U)&7, since 60+64S+8jb == 4 mod 8):
// broadcast h[k][0..7] via readlane from slice S, FMA, reload slot from k+8
#define HSTEP(S, U) { \
    int ln = jb8 + (U); \
    float b0=RL(hsa##S.x,ln), b1=RL(hsa##S.y,ln), b2=RL(hsa##S.z,ln), b3=RL(hsa##S.w,ln); \
    float b4=RL(hsb##S.x,ln), b5=RL(hsb##S.y,ln), b6=RL(hsb##S.z,ln), b7=RL(hsb##S.w,ln); \
    FMA24(wR[(4+(U))&7],wZ[(4+(U))&7],wN[(4+(U))&7], b0,b1,b2,b3,b4,b5,b6,b7, hr,hz,hn); \
    { int ro = (60 + 64*(S) + jb8 + (U) + 8) * G3; const int SL=(4+(U))&7; \
      wR[SL]=pw[ro]; wZ[SL]=pw[ro+HID]; wN[SL]=pw[ro+2*HID]; } \
}

#define H8(S) HSTEP(S,0) HSTEP(S,1) HSTEP(S,2) HSTEP(S,3) \
              HSTEP(S,4) HSTEP(S,5) HSTEP(S,6) HSTEP(S,7)

__global__ __launch_bounds__(256, 2) void k_gru(
    const float* __restrict__ emb,
    const float* __restrict__ wcat_f, const float* __restrict__ bih_f, const float* __restrict__ bhh_f,
    const float* __restrict__ wcat_b, const float* __restrict__ bih_b, const float* __restrict__ bhh_b,
    float* __restrict__ tup) {

    const bool rev = blockIdx.x & 1;
    const int  n0  = (blockIdx.x >> 1) * MB;
    const float* wcat = rev ? wcat_b : wcat_f;
    const float* bih  = rev ? bih_b  : bih_f;
    const float* bhh  = rev ? bhh_b  : bhh_f;
    const int tid = threadIdx.x;
    const bool act = tid < HID;

    __shared__ float s_s[SROWS][MB];   // 10112 B: rows 0..59 e, 60..315 h(+pad)

    for (int i = tid; i < SROWS * MB; i += 256) ((float*)s_s)[i] = 0.f;

    float bir = 0.f, biz = 0.f, bin_ = 0.f, bhr = 0.f, bhz = 0.f, bhn = 0.f;
    if (act) {
        bir = bih[tid]; biz = bih[HID + tid]; bin_ = bih[2 * HID + tid];
        bhr = bhh[tid]; bhz = bhh[HID + tid]; bhn = bhh[2 * HID + tid];
    }

    const float* pw = wcat + tid;  // row k: pw[k*G3] (r), +HID (z), +2*HID (n)

    // rolling weight slots 0..7 <- rows 0..7 (slot == row mod 8)
    float wR[KU], wZ[KU], wN[KU];
    if (act) {
#pragma unroll
        for (int u = 0; u < KU; ++u) {
            int kk = u * G3; wR[u] = pw[kk]; wZ[u] = pw[kk + HID]; wN[u] = pw[kk + 2 * HID];
        }
    }

    const int lane = tid & 63;
    __syncthreads();

    for (int t = 0; t < SEQ; ++t) {
        const int tt = rev ? (SEQ - 1 - t) : t;

        // stage emb tile into s_s rows 0..59 (480 elems, 256 threads)
        for (int i = tid; i < DIN * MB; i += 256) {
            int n = i / DIN, k = i - n * DIN;
            s_s[k][n] = emb[((long)(n0 + n) * SEQ + tt) * DIN + k];
        }
        __syncthreads();   // A: e rows staged, h rows published

        // slurp the full h vector into per-lane slices (all lanes, all waves):
        // slice s, lane L = h row 60+64s+L; 8 per-lane ds_read_b128 per wave
        float4 hsa0 = *(const float4*)&s_s[ 60 + lane][0];
        float4 hsb0 = *(const float4*)&s_s[ 60 + lane][4];
        float4 hsa1 = *(const float4*)&s_s[124 + lane][0];
        float4 hsb1 = *(const float4*)&s_s[124 + lane][4];
        float4 hsa2 = *(const float4*)&s_s[188 + lane][0];
        float4 hsb2 = *(const float4*)&s_s[188 + lane][4];
        float4 hsa3 = *(const float4*)&s_s[252 + lane][0];
        float4 hsb3 = *(const float4*)&s_s[252 + lane][4];

        float ar[MB], az[MB], an[MB], hr[MB], hz[MB], hn[MB];
        if (act) {
#pragma unroll
            for (int n = 0; n < MB; ++n) {
                ar[n] = bir; az[n] = biz; an[n] = bin_;
                hr[n] = bhr; hz[n] = bhz; hn[n] = bhn;
            }
            float4 ra0 = *(const float4*)&s_s[0][0];
            float4 ra1 = *(const float4*)&s_s[0][4];

            // ---- input projection: k = 0..59 (LDS-uniform path) ----
#pragma clang loop unroll(disable)
            for (int eb8 = 0; eb8 < 56; eb8 += 8) {
                ESTEP(0) ESTEP(1) ESTEP(2) ESTEP(3)
                ESTEP(4) ESTEP(5) ESTEP(6) ESTEP(7)
            }
            { const int eb8 = 56; ESTEP(0) ESTEP(1) ESTEP(2) ESTEP(3) }  // k=56..59

            // ---- hidden projection: k = 60..289 (readlane path) ----
#pragma clang loop unroll(disable)
            for (int jb8 = 0; jb8 < 64; jb8 += 8) { H8(0) }   // k  60..123
#pragma clang loop unroll(disable)
            for (int jb8 = 0; jb8 < 64; jb8 += 8) { H8(1) }   // k 124..187
#pragma clang loop unroll(disable)
            for (int jb8 = 0; jb8 < 64; jb8 += 8) { H8(2) }   // k 188..251
#pragma clang loop unroll(disable)
            for (int jb8 = 0; jb8 < 32; jb8 += 8) { H8(3) }   // k 252..283
            { const int jb8 = 32;                              // k 284..289
              HSTEP(3,0) HSTEP(3,1) HSTEP(3,2) HSTEP(3,3) HSTEP(3,4) HSTEP(3,5) }
        }
        __syncthreads();   // B: all waves done reading s_s / slices

        // thread-local gate combine -> new h; publish to LDS + tup
        if (act) {
#pragma unroll
            for (int n = 0; n < MB; ++n) {
                float r  = 1.f / (1.f + expf(-(ar[n] + hr[n])));
                float z  = 1.f / (1.f + expf(-(az[n] + hz[n])));
                float nn = tanhf(an[n] + r * hn[n]);
                float hold = s_s[DIN + tid][n];
                float hnew = (1.f - z) * nn + z * hold;
                s_s[DIN + tid][n] = hnew;
                atomicAdd(&tup[((long)(n0 + n) * SEQ + tt) * HID + tid], hnew);
            }
        }
    }
}

// ---------------- word-level attention ----------------
__global__ __launch_bounds__(256) void k_wordattn(
    const float* __restrict__ tup, const float* __restrict__ attw,
    const float* __restrict__ sen_a, const float* __restrict__ sen_r,
    float* __restrict__ repre, float* __restrict__ sbuf) {
    const int n = blockIdx.x, tid = threadIdx.x;
    __shared__ float tl[SEQ * HID];   // 64400 B
    __shared__ float sc[SEQ];
    __shared__ float red[4];
    for (int i = tid; i < SEQ * HID; i += 256) tl[i] = tup[(long)n * SEQ * HID + i];
    __syncthreads();
    if (tid < SEQ) {
        float s = 0.f;
        for (int h = 0; h < HID; ++h) s += tanhf(tl[tid * HID + h]) * attw[h];
        sc[tid] = s;
    }
    __syncthreads();
    if (tid == 0) {
        float m = sc[0];
        for (int t = 1; t < SEQ; ++t) m = fmaxf(m, sc[t]);
        float ssum = 0.f;
        for (int t = 0; t < SEQ; ++t) { float e = expf(sc[t] - m); sc[t] = e; ssum += e; }
        float inv = 1.f / ssum;
        for (int t = 0; t < SEQ; ++t) sc[t] *= inv;
    }
    __syncthreads();
    float part = 0.f;
    if (tid < HID) {
        float r = 0.f;
        for (int t = 0; t < SEQ; ++t) r = fmaf(sc[t], tl[t * HID + tid], r);
        float rep = tanhf(r);
        repre[(long)n * HID + tid] = rep;
        part = rep * sen_a[tid] * sen_r[tid];
    }
    for (int off = 32; off; off >>= 1) part += __shfl_down(part, off, 64);
    if ((tid & 63) == 0) red[tid >> 6] = part;
    __syncthreads();
    if (tid == 0) sbuf[n] = red[0] + red[1] + red[2] + red[3];
}

// ---------------- bag attention + logits + loss + prob + acc ----------------
__global__ __launch_bounds__(256) void k_bag(
    const float* __restrict__ repre, const float* __restrict__ sbuf,
    const float* __restrict__ rel, const float* __restrict__ sen_d,
    const float* __restrict__ y, float* __restrict__ out, float* __restrict__ bagloss) {
    const int b = blockIdx.x, tid = threadIdx.x;
    __shared__ float al[BAGSZ];
    __shared__ float ss[HID];
    __shared__ float lg[NREL];
    if (tid == 0) {
        float m = -1e30f;
        for (int i = 0; i < BAGSZ; ++i) m = fmaxf(m, sbuf[b * BAGSZ + i]);
        float s = 0.f;
        for (int i = 0; i < BAGSZ; ++i) { float e = expf(sbuf[b * BAGSZ + i] - m); al[i] = e; s += e; }
        float inv = 1.f / s;
        for (int i = 0; i < BAGSZ; ++i) al[i] *= inv;
    }
    __syncthreads();
    if (tid < HID) {
        float acc = 0.f;
        for (int i = 0; i < BAGSZ; ++i)
            acc = fmaf(al[i], repre[(long)(b * BAGSZ + i) * HID + tid], acc);
        ss[tid] = acc;
    }
    __syncthreads();
    if (tid < NREL) {
        float acc = sen_d[tid];
        for (int h = 0; h < HID; ++h) acc = fmaf(ss[h], rel[tid * HID + h], acc);
        lg[tid] = acc;
    }
    __syncthreads();
    if (tid == 0) {
        float m = -1e30f; int am = 0;
        for (int r = 0; r < NREL; ++r) if (lg[r] > m) { m = lg[r]; am = r; }
        float s = 0.f;
        for (int r = 0; r < NREL; ++r) s += expf(lg[r] - m);
        float inv = 1.f / s;
        float ym = -1e30f; int ay = 0;
        for (int r = 0; r < NREL; ++r) { float yy = y[b * NREL + r]; if (yy > ym) { ym = yy; ay = r; } }
        out[1 + b] = (am == ay) ? 1.f : 0.f;
        float loss = 0.f;
        for (int r = 0; r < NREL; ++r) {
            float l = lg[r], yy = y[b * NREL + r];
            loss += fmaxf(l, 0.f) - l * yy + log1pf(expf(-fabsf(l)));
            out[1 + NBAG + b * NREL + r] = expf(l - m) * inv;
        }
        bagloss[b] = loss / NREL;
    }
}

__global__ void k_final(const float* __restrict__ bagloss, float* __restrict__ out) {
    if (blockIdx.x == 0 && threadIdx.x == 0) {
        float s = 0.f;
        for (int i = 0; i < NBAG; ++i) s += bagloss[i];
        out[0] = s;
    }
}

// ---------------- host launcher ----------------
extern "C" void kernel_launch(void* const* d_in, const int* in_sizes, int n_in,
                              void* d_out, int out_size, void* d_ws, size_t ws_size,
                              hipStream_t stream) {
    const int*   sent   = (const int*)d_in[0];
    const int*   pos1   = (const int*)d_in[1];
    const int*   pos2   = (const int*)d_in[2];
    // d_in[3] = total_shape (bag layout is fixed: 64 bags x 32)
    const float* ybatch = (const float*)d_in[4];
    const float* wemb   = (const float*)d_in[5];
    const float* p1tab  = (const float*)d_in[6];
    const float* p2tab  = (const float*)d_in[7];
    const float* Wih_f  = (const float*)d_in[8];
    const float* Whh_f  = (const float*)d_in[9];
    const float* bih_f  = (const float*)d_in[10];
    const float* bhh_f  = (const float*)d_in[11];
    const float* Wih_b  = (const float*)d_in[12];
    const float* Whh_b  = (const float*)d_in[13];
    const float* bih_b  = (const float*)d_in[14];
    const float* bhh_b  = (const float*)d_in[15];
    const float* attw   = (const float*)d_in[16];
    const float* sen_a  = (const float*)d_in[17];
    const float* sen_r  = (const float*)d_in[18];
    const float* rel    = (const float*)d_in[19];
    const float* sen_d  = (const float*)d_in[20];
    float* out = (float*)d_out;

    float* ws = (float*)d_ws;
    size_t off = 0;
    float* emb    = ws + off; off += (size_t)NTOT * SEQ * DIN;   // 8,601,600
    float* wcat_f = ws + off; off += (size_t)WROWS * G3;         // 205,620
    float* wcat_b = ws + off; off += (size_t)WROWS * G3;
    float* tup    = ws + off; off += (size_t)NTOT * SEQ * HID;   // 32,998,400
    float* repre  = ws + off; off += (size_t)NTOT * HID;
    float* sbuf   = ws + off; off += (size_t)NTOT;
    float* bagloss= ws + off; off += (size_t)NBAG;

    const long tupN = (long)NTOT * SEQ * HID;
    k_zero<<<(int)((tupN + 255) / 256), 256, 0, stream>>>(tup, tupN);

    const long embN = (long)NTOT * SEQ * DIN;
    k_embed<<<(int)((embN + 255) / 256), 256, 0, stream>>>(sent, pos1, pos2, wemb, p1tab, p2tab, emb);

    // wcat rows 0..59 = Wih^T, rows 60..289 = Whh^T, rows 290..297 = dup(row&7)
    k_transpose<<<(G3 * DIN + 255) / 256, 256, 0, stream>>>(Wih_f, wcat_f, G3, DIN);
    k_transpose<<<(G3 * HID + 255) / 256, 256, 0, stream>>>(Whh_f, wcat_f + (size_t)DIN * G3, G3, HID);
    k_transpose<<<(G3 * DIN + 255) / 256, 256, 0, stream>>>(Wih_b, wcat_b, G3, DIN);
    k_transpose<<<(G3 * HID + 255) / 256, 256, 0, stream>>>(Whh_b, wcat_b + (size_t)DIN * G3, G3, HID);
    k_dupe<<<(8 * G3 + 255) / 256, 256, 0, stream>>>(wcat_f);
    k_dupe<<<(8 * G3 + 255) / 256, 256, 0, stream>>>(wcat_b);

    k_gru<<<(NTOT / MB) * 2, 256, 0, stream>>>(emb,
        wcat_f, bih_f, bhh_f,
        wcat_b, bih_b, bhh_b, tup);

    k_wordattn<<<NTOT, 256, 0, stream>>>(tup, attw, sen_a, sen_r, repre, sbuf);

    k_bag<<<NBAG, 256, 0, stream>>>(repre, sbuf, rel, sen_d, ybatch, out, bagloss);

    k_final<<<1, 64, 0, stream>>>(bagloss, out);
}

// Round 16
// 2514.463 us; speedup vs baseline: 1.4866x; 1.2373x over previous
//
#include <hip/hip_runtime.h>
#include <hip/hip_bf16.h>
#include <math.h>

#define SEQ 70
#define HID 230
#define G3  690
#define EMBD 50
#define DIN 60
#define NTOT 2048
#define NREL 100
#define NBAG 64
#define BAGSZ 32
#define PDIM 5
#define MB 8       // sentences per GRU block
#define KU 10      // k-rows per rolling weight buffer
#define KTOT 290   // fused path: DIN+HID unified K stream
#define SROWS_F 292 // fused path LDS rows (290 + 2 pad)
#define SROWS_H 232 // split path LDS rows (230 h + 2 pad)
#define WROWS_H 240 // whh rows: 0..229 real, 230..239 dup of rows 0..9
#define TCH 10     // k_gi timesteps per block

// ---------------- prep kernels ----------------

__global__ void k_zero(float* p, long n) {
    long i = (long)blockIdx.x * 256 + threadIdx.x;
    if (i < n) p[i] = 0.f;
}

__global__ void k_embed(const int* __restrict__ sent, const int* __restrict__ p1,
                        const int* __restrict__ p2,  const float* __restrict__ wemb,
                        const float* __restrict__ t1, const float* __restrict__ t2,
                        float* __restrict__ emb) {
    long idx = (long)blockIdx.x * 256 + threadIdx.x;
    long total = (long)NTOT * SEQ * DIN;
    if (idx >= total) return;
    int nt = (int)(idx / DIN);
    int j  = (int)(idx % DIN);
    float v;
    if (j < EMBD)            v = wemb[(long)sent[nt] * EMBD + j];
    else if (j < EMBD + PDIM) v = t1[p1[nt] * PDIM + (j - EMBD)];
    else                      v = t2[p2[nt] * PDIM + (j - EMBD - PDIM)];
    emb[idx] = v;
}

// in[g*K+k] -> out[k*G+g]
__global__ void k_transpose(const float* __restrict__ in, float* __restrict__ out,
                            int G, int K) {
    int idx = blockIdx.x * 256 + threadIdx.x;
    if (idx >= G * K) return;
    int g = idx / K, k = idx % K;
    out[k * G + g] = in[idx];
}

// whh dup: rows 230..239 <- rows 0..9 (rolling prefetch wrap for next timestep)
__global__ void k_dupeh(float* __restrict__ w) {
    int idx = blockIdx.x * 256 + threadIdx.x;
    if (idx >= 10 * G3) return;
    int i = idx / G3, g = idx % G3;
    w[(HID + i) * G3 + g] = w[i * G3 + g];
}

// ---------------- shared GRU macros (R9-verified rolling pipeline) ----------

#define ROWLD(R0,R1, kk) { const float4* _p = (const float4*)s_s[kk]; \
    R0 = _p[0]; R1 = _p[1]; }

#define FMA4(WR,WZ,WN, Q, B, AR,AZ,AN) \
    AR[B+0]=fmaf(WR,Q.x,AR[B+0]); AZ[B+0]=fmaf(WZ,Q.x,AZ[B+0]); AN[B+0]=fmaf(WN,Q.x,AN[B+0]); \
    AR[B+1]=fmaf(WR,Q.y,AR[B+1]); AZ[B+1]=fmaf(WZ,Q.y,AZ[B+1]); AN[B+1]=fmaf(WN,Q.y,AN[B+1]); \
    AR[B+2]=fmaf(WR,Q.z,AR[B+2]); AZ[B+2]=fmaf(WZ,Q.z,AZ[B+2]); AN[B+2]=fmaf(WN,Q.z,AN[B+2]); \
    AR[B+3]=fmaf(WR,Q.w,AR[B+3]); AZ[B+3]=fmaf(WZ,Q.w,AZ[B+3]); AN[B+3]=fmaf(WN,Q.w,AN[B+3]);

#define FMA8(WR,WZ,WN, AR,AZ,AN, Q0,Q1) \
    FMA4(WR,WZ,WN, Q0, 0, AR,AZ,AN) FMA4(WR,WZ,WN, Q1, 4, AR,AZ,AN)

// two k-steps with rolling weight prefetch: consume w[UE] for block KB, then
// reload the SAME slot with block KB+1 row UE (distance 10 rows).
#define U2R(KB, UE, AR,AZ,AN) \
    FMA8(wR[UE],wZ[UE],wN[UE], AR,AZ,AN, ra0,ra1); \
    ROWLD(ra0,ra1, (KB)*KU+(UE)+2); \
    { int _kk = (((KB)+1)*KU + (UE)) * G3; wR[UE]=pr[_kk]; wZ[UE]=pz[_kk]; wN[UE]=pn[_kk]; } \
    FMA8(wR[UE+1],wZ[UE+1],wN[UE+1], AR,AZ,AN, rb0,rb1); \
    ROWLD(rb0,rb1, (KB)*KU+(UE)+3); \
    { int _kk = (((KB)+1)*KU + (UE)+1) * G3; wR[UE+1]=pr[_kk]; wZ[UE+1]=pz[_kk]; wN[UE+1]=pn[_kk]; }

// epilogue variant (fused path): wrap the weight prefetch to block 0
#define U2W(KB, UE, AR,AZ,AN) \
    FMA8(wR[UE],wZ[UE],wN[UE], AR,AZ,AN, ra0,ra1); \
    ROWLD(ra0,ra1, (KB)*KU+(UE)+2); \
    { int _kk = (UE) * G3; wR[UE]=pr[_kk]; wZ[UE]=pz[_kk]; wN[UE]=pn[_kk]; } \
    FMA8(wR[UE+1],wZ[UE+1],wN[UE+1], AR,AZ,AN, rb0,rb1); \
    ROWLD(rb0,rb1, (KB)*KU+(UE)+3); \
    { int _kk = ((UE)+1) * G3; wR[UE+1]=pr[_kk]; wZ[UE+1]=pz[_kk]; wN[UE+1]=pn[_kk]; }

#define BLK10R(KB, AR,AZ,AN) \
    U2R(KB, 0, AR,AZ,AN) U2R(KB, 2, AR,AZ,AN) U2R(KB, 4, AR,AZ,AN) \
    U2R(KB, 6, AR,AZ,AN) U2R(KB, 8, AR,AZ,AN)

#define BLK10W(KB, AR,AZ,AN) \
    U2W(KB, 0, AR,AZ,AN) U2W(KB, 2, AR,AZ,AN) U2W(KB, 4, AR,AZ,AN) \
    U2W(KB, 6, AR,AZ,AN) U2W(KB, 8, AR,AZ,AN)

// ---------------- split path: input-projection pre-GEMM -------------------
// gi[dir][n][t][g] = bih[g] + sum_{d ascending} emb[n,t,d]*Wih[g][d]
// -- identical chain order to the fused e-part -> bitwise-equal contribution.
// grid = (NTOT/MB) * (SEQ/TCH) * 2 = 3584 blocks; no recurrence -> TLP hides
// all latency; this removes 60/290 of the serial kernel's work.
__global__ __launch_bounds__(256, 2) void k_gi(
    const float* __restrict__ emb,
    const float* __restrict__ wih_f, const float* __restrict__ bih_f,
    const float* __restrict__ wih_b, const float* __restrict__ bih_b,
    float* __restrict__ gi) {
    const int bid = blockIdx.x;
    const int dir = bid & 1;
    const int r   = bid >> 1;
    const int tc  = r % (SEQ / TCH);
    const int n0  = (r / (SEQ / TCH)) * MB;
    const float* wih = dir ? wih_b : wih_f;
    const float* bih = dir ? bih_b : bih_f;
    const int tid = threadIdx.x;
    const bool act = tid < HID;

    __shared__ float e_s[DIN][MB];

    float bir = 0.f, biz = 0.f, bin_ = 0.f;
    if (act) { bir = bih[tid]; biz = bih[HID + tid]; bin_ = bih[2 * HID + tid]; }
    const float* pw = wih + tid;

    for (int tt = tc * TCH; tt < tc * TCH + TCH; ++tt) {
        for (int i = tid; i < DIN * MB; i += 256) {
            int n = i / DIN, k = i - n * DIN;
            e_s[k][n] = emb[((long)(n0 + n) * SEQ + tt) * DIN + k];
        }
        __syncthreads();
        if (act) {
            float ar[MB], az[MB], an[MB];
#pragma unroll
            for (int n = 0; n < MB; ++n) { ar[n] = bir; az[n] = biz; an[n] = bin_; }
            for (int k = 0; k < DIN; ++k) {
                float wr = pw[k * G3], wz = pw[k * G3 + HID], wn = pw[k * G3 + 2 * HID];
                float4 e0 = *(const float4*)&e_s[k][0];
                float4 e1 = *(const float4*)&e_s[k][4];
                FMA8(wr, wz, wn, ar, az, an, e0, e1)
            }
#pragma unroll
            for (int n = 0; n < MB; ++n) {
                long gb = ((long)(dir ? NTOT : 0) + (n0 + n)) * ((long)SEQ * G3) + (long)tt * G3;
                gi[gb + tid] = ar[n];
                gi[gb + HID + tid] = az[n];
                gi[gb + 2 * HID + tid] = an[n];
            }
        }
        __syncthreads();
    }
}

// ---------------- split path: recurrent kernel (hh only) ------------------
// R9 structure minus the e-part: K-loop = 230 whh rows (23 blocks of 10),
// rolling slots wrap via dup rows 230..239 (= rows 0..9). Accumulators:
// ar/az/an loaded from gi (= the fused e-sums), hr/hz/hn from bhh, both
// k-ascending -> bitwise identical to R9. s_s row j = h element j.
__global__ __launch_bounds__(256, 2) void k_gru2(
    const float* __restrict__ gi,
    const float* __restrict__ whh_f, const float* __restrict__ bhh_f,
    const float* __restrict__ whh_b, const float* __restrict__ bhh_b,
    float* __restrict__ tup) {

    const bool rev = blockIdx.x & 1;
    const int  n0  = (blockIdx.x >> 1) * MB;
    const float* whh = rev ? whh_b : whh_f;
    const float* bhh = rev ? bhh_b : bhh_f;
    const int tid = threadIdx.x;
    const bool act = tid < HID;

    __shared__ float s_s[SROWS_H][MB];   // 7424 B: rows 0..229 h, 230..231 pad

    for (int i = tid; i < SROWS_H * MB; i += 256) ((float*)s_s)[i] = 0.f;

    float bhr = 0.f, bhz = 0.f, bhn = 0.f;
    if (act) { bhr = bhh[tid]; bhz = bhh[HID + tid]; bhn = bhh[2 * HID + tid]; }

    const float* pr = whh + tid;
    const float* pz = whh + HID + tid;
    const float* pn = whh + 2 * HID + tid;

    float wR[KU], wZ[KU], wN[KU];
    if (act) {
#pragma unroll
        for (int u = 0; u < KU; ++u) {
            int kk = u * G3; wR[u] = pr[kk]; wZ[u] = pz[kk]; wN[u] = pn[kk];
        }
    }

    __syncthreads();

    for (int t = 0; t < SEQ; ++t) {
        const int tt = rev ? (SEQ - 1 - t) : t;

        float ar[MB], az[MB], an[MB], hr[MB], hz[MB], hn[MB];
        if (act) {
            // ar/az/an <- precomputed input projection (bias already inside)
#pragma unroll
            for (int n = 0; n < MB; ++n) {
                long gb = ((long)(rev ? NTOT : 0) + (n0 + n)) * ((long)SEQ * G3) + (long)tt * G3;
                ar[n] = gi[gb + tid];
                az[n] = gi[gb + HID + tid];
                an[n] = gi[gb + 2 * HID + tid];
                hr[n] = bhr; hz[n] = bhz; hn[n] = bhn;
            }
            float4 ra0, ra1, rb0, rb1;
            ROWLD(ra0, ra1, 0)
            ROWLD(rb0, rb1, 1)

            // hidden projection: 23 blocks of 10 (rows 0..229); block 22's
            // prefetch reads dup rows 230..239 = rows 0..9 for the next t
#pragma clang loop unroll(disable)
            for (int kb = 0; kb < 23; ++kb) { BLK10R(kb, hr, hz, hn) }
        }
        __syncthreads();   // B: all waves done reading s_s

        if (act) {
#pragma unroll
            for (int n = 0; n < MB; ++n) {
                float r  = 1.f / (1.f + expf(-(ar[n] + hr[n])));
                float z  = 1.f / (1.f + expf(-(az[n] + hz[n])));
                float nn = tanhf(an[n] + r * hn[n]);
                float hold = s_s[tid][n];
                float hnew = (1.f - z) * nn + z * hold;
                s_s[tid][n] = hnew;
                atomicAdd(&tup[((long)(n0 + n) * SEQ + tt) * HID + tid], hnew);
            }
        }
        __syncthreads();   // A: h writes visible before next step's reads
    }
}

// ---------------- fallback: R9 fused kernel (verified 2574 us, absmax 0) --
__global__ __launch_bounds__(256, 2) void k_gruF(
    const float* __restrict__ emb,
    const float* __restrict__ wcat_f, const float* __restrict__ bih_f, const float* __restrict__ bhh_f,
    const float* __restrict__ wcat_b, const float* __restrict__ bih_b, const float* __restrict__ bhh_b,
    float* __restrict__ tup) {

    const bool rev = blockIdx.x & 1;
    const int  n0  = (blockIdx.x >> 1) * MB;
    const float* wcat = rev ? wcat_b : wcat_f;
    const float* bih  = rev ? bih_b  : bih_f;
    const float* bhh  = rev ? bhh_b  : bhh_f;
    const int tid = threadIdx.x;
    const bool act = tid < HID;

    __shared__ float s_s[SROWS_F][MB];

    for (int i = tid; i < SROWS_F * MB; i += 256) ((float*)s_s)[i] = 0.f;

    float bir = 0.f, biz = 0.f, bin_ = 0.f, bhr = 0.f, bhz = 0.f, bhn = 0.f;
    if (act) {
        bir = bih[tid]; biz = bih[HID + tid]; bin_ = bih[2 * HID + tid];
        bhr = bhh[tid]; bhz = bhh[HID + tid]; bhn = bhh[2 * HID + tid];
    }

    const float* pr = wcat + tid;
    const float* pz = wcat + HID + tid;
    const float* pn = wcat + 2 * HID + tid;

    float wR[KU], wZ[KU], wN[KU];
    if (act) {
#pragma unroll
        for (int u = 0; u < KU; ++u) {
            int kk = u * G3; wR[u] = pr[kk]; wZ[u] = pz[kk]; wN[u] = pn[kk];
        }
    }

    __syncthreads();

    for (int t = 0; t < SEQ; ++t) {
        const int tt = rev ? (SEQ - 1 - t) : t;

        for (int i = tid; i < DIN * MB; i += 256) {
            int n = i / DIN, k = i - n * DIN;
            s_s[k][n] = emb[((long)(n0 + n) * SEQ + tt) * DIN + k];
        }
        __syncthreads();

        float ar[MB], az[MB], an[MB], hr[MB], hz[MB], hn[MB];
        if (act) {
#pragma unroll
            for (int n = 0; n < MB; ++n) {
                ar[n] = bir; az[n] = biz; an[n] = bin_;
                hr[n] = bhr; hz[n] = bhz; hn[n] = bhn;
            }
            float4 ra0, ra1, rb0, rb1;
            ROWLD(ra0, ra1, 0)
            ROWLD(rb0, rb1, 1)

#pragma clang loop unroll(disable)
            for (int kb = 0; kb < 6; ++kb) { BLK10R(kb, ar, az, an) }
#pragma clang loop unroll(disable)
            for (int kb = 6; kb < 28; ++kb) { BLK10R(kb, hr, hz, hn) }
            BLK10W(28, hr, hz, hn)
        }
        __syncthreads();

        if (act) {
#pragma unroll
            for (int n = 0; n < MB; ++n) {
                float r  = 1.f / (1.f + expf(-(ar[n] + hr[n])));
                float z  = 1.f / (1.f + expf(-(az[n] + hz[n])));
                float nn = tanhf(an[n] + r * hn[n]);
                float hold = s_s[DIN + tid][n];
                float hnew = (1.f - z) * nn + z * hold;
                s_s[DIN + tid][n] = hnew;
                atomicAdd(&tup[((long)(n0 + n) * SEQ + tt) * HID + tid], hnew);
            }
        }
    }
}

// ---------------- word-level attention ----------------
__global__ __launch_bounds__(256) void k_wordattn(
    const float* __restrict__ tup, const float* __restrict__ attw,
    const float* __restrict__ sen_a, const float* __restrict__ sen_r,
    float* __restrict__ repre, float* __restrict__ sbuf) {
    const int n = blockIdx.x, tid = threadIdx.x;
    __shared__ float tl[SEQ * HID];   // 64400 B
    __shared__ float sc[SEQ];
    __shared__ float red[4];
    for (int i = tid; i < SEQ * HID; i += 256) tl[i] = tup[(long)n * SEQ * HID + i];
    __syncthreads();
    if (tid < SEQ) {
        float s = 0.f;
        for (int h = 0; h < HID; ++h) s += tanhf(tl[tid * HID + h]) * attw[h];
        sc[tid] = s;
    }
    __syncthreads();
    if (tid == 0) {
        float m = sc[0];
        for (int t = 1; t < SEQ; ++t) m = fmaxf(m, sc[t]);
        float ssum = 0.f;
        for (int t = 0; t < SEQ; ++t) { float e = expf(sc[t] - m); sc[t] = e; ssum += e; }
        float inv = 1.f / ssum;
        for (int t = 0; t < SEQ; ++t) sc[t] *= inv;
    }
    __syncthreads();
    float part = 0.f;
    if (tid < HID) {
        float r = 0.f;
        for (int t = 0; t < SEQ; ++t) r = fmaf(sc[t], tl[t * HID + tid], r);
        float rep = tanhf(r);
        repre[(long)n * HID + tid] = rep;
        part = rep * sen_a[tid] * sen_r[tid];
    }
    for (int off = 32; off; off >>= 1) part += __shfl_down(part, off, 64);
    if ((tid & 63) == 0) red[tid >> 6] = part;
    __syncthreads();
    if (tid == 0) sbuf[n] = red[0] + red[1] + red[2] + red[3];
}

// ---------------- bag attention + logits + loss + prob + acc ----------------
__global__ __launch_bounds__(256) void k_bag(
    const float* __restrict__ repre, const float* __restrict__ sbuf,
    const float* __restrict__ rel, const float* __restrict__ sen_d,
    const float* __restrict__ y, float* __restrict__ out, float* __restrict__ bagloss) {
    const int b = blockIdx.x, tid = threadIdx.x;
    __shared__ float al[BAGSZ];
    __shared__ float ss[HID];
    __shared__ float lg[NREL];
    if (tid == 0) {
        float m = -1e30f;
        for (int i = 0; i < BAGSZ; ++i) m = fmaxf(m, sbuf[b * BAGSZ + i]);
        float s = 0.f;
        for (int i = 0; i < BAGSZ; ++i) { float e = expf(sbuf[b * BAGSZ + i] - m); al[i] = e; s += e; }
        float inv = 1.f / s;
        for (int i = 0; i < BAGSZ; ++i) al[i] *= inv;
    }
    __syncthreads();
    if (tid < HID) {
        float acc = 0.f;
        for (int i = 0; i < BAGSZ; ++i)
            acc = fmaf(al[i], repre[(long)(b * BAGSZ + i) * HID + tid], acc);
        ss[tid] = acc;
    }
    __syncthreads();
    if (tid < NREL) {
        float acc = sen_d[tid];
        for (int h = 0; h < HID; ++h) acc = fmaf(ss[h], rel[tid * HID + h], acc);
        lg[tid] = acc;
    }
    __syncthreads();
    if (tid == 0) {
        float m = -1e30f; int am = 0;
        for (int r = 0; r < NREL; ++r) if (lg[r] > m) { m = lg[r]; am = r; }
        float s = 0.f;
        for (int r = 0; r < NREL; ++r) s += expf(lg[r] - m);
        float inv = 1.f / s;
        float ym = -1e30f; int ay = 0;
        for (int r = 0; r < NREL; ++r) { float yy = y[b * NREL + r]; if (yy > ym) { ym = yy; ay = r; } }
        out[1 + b] = (am == ay) ? 1.f : 0.f;
        float loss = 0.f;
        for (int r = 0; r < NREL; ++r) {
            float l = lg[r], yy = y[b * NREL + r];
            loss += fmaxf(l, 0.f) - l * yy + log1pf(expf(-fabsf(l)));
            out[1 + NBAG + b * NREL + r] = expf(l - m) * inv;
        }
        bagloss[b] = loss / NREL;
    }
}

__global__ void k_final(const float* __restrict__ bagloss, float* __restrict__ out) {
    if (blockIdx.x == 0 && threadIdx.x == 0) {
        float s = 0.f;
        for (int i = 0; i < NBAG; ++i) s += bagloss[i];
        out[0] = s;
    }
}

// ---------------- host launcher ----------------
extern "C" void kernel_launch(void* const* d_in, const int* in_sizes, int n_in,
                              void* d_out, int out_size, void* d_ws, size_t ws_size,
                              hipStream_t stream) {
    const int*   sent   = (const int*)d_in[0];
    const int*   pos1   = (const int*)d_in[1];
    const int*   pos2   = (const int*)d_in[2];
    // d_in[3] = total_shape (bag layout is fixed: 64 bags x 32)
    const float* ybatch = (const float*)d_in[4];
    const float* wemb   = (const float*)d_in[5];
    const float* p1tab  = (const float*)d_in[6];
    const float* p2tab  = (const float*)d_in[7];
    const float* Wih_f  = (const float*)d_in[8];
    const float* Whh_f  = (const float*)d_in[9];
    const float* bih_f  = (const float*)d_in[10];
    const float* bhh_f  = (const float*)d_in[11];
    const float* Wih_b  = (const float*)d_in[12];
    const float* Whh_b  = (const float*)d_in[13];
    const float* bih_b  = (const float*)d_in[14];
    const float* bhh_b  = (const float*)d_in[15];
    const float* attw   = (const float*)d_in[16];
    const float* sen_a  = (const float*)d_in[17];
    const float* sen_r  = (const float*)d_in[18];
    const float* rel    = (const float*)d_in[19];
    const float* sen_d  = (const float*)d_in[20];
    float* out = (float*)d_out;

    float* ws = (float*)d_ws;
    size_t off = 0;
    float* emb    = ws + off; off += (size_t)NTOT * SEQ * DIN;      // 8,601,600
    float* wcat_f = ws + off; off += (size_t)SROWS_F * G3;          // fused path
    float* wcat_b = ws + off; off += (size_t)SROWS_F * G3;
    float* wih_f  = ws + off; off += (size_t)DIN * G3;              // split path
    float* wih_b  = ws + off; off += (size_t)DIN * G3;
    float* whh_f  = ws + off; off += (size_t)WROWS_H * G3;
    float* whh_b  = ws + off; off += (size_t)WROWS_H * G3;
    float* tup    = ws + off; off += (size_t)NTOT * SEQ * HID;      // 32,998,400
    float* repre  = ws + off; off += (size_t)NTOT * HID;
    float* sbuf   = ws + off; off += (size_t)NTOT;
    float* bagloss= ws + off; off += (size_t)NBAG;
    float* gi     = ws + off; off += (size_t)2 * NTOT * SEQ * G3;   // 197,836,800
    const size_t need_split = off;

    const bool split = (ws_size / sizeof(float)) >= need_split;

    const long tupN = (long)NTOT * SEQ * HID;
    k_zero<<<(int)((tupN + 255) / 256), 256, 0, stream>>>(tup, tupN);

    const long embN = (long)NTOT * SEQ * DIN;
    k_embed<<<(int)((embN + 255) / 256), 256, 0, stream>>>(sent, pos1, pos2, wemb, p1tab, p2tab, emb);

    if (split) {
        k_transpose<<<(G3 * DIN + 255) / 256, 256, 0, stream>>>(Wih_f, wih_f, G3, DIN);
        k_transpose<<<(G3 * DIN + 255) / 256, 256, 0, stream>>>(Wih_b, wih_b, G3, DIN);
        k_transpose<<<(G3 * HID + 255) / 256, 256, 0, stream>>>(Whh_f, whh_f, G3, HID);
        k_transpose<<<(G3 * HID + 255) / 256, 256, 0, stream>>>(Whh_b, whh_b, G3, HID);
        k_dupeh<<<(10 * G3 + 255) / 256, 256, 0, stream>>>(whh_f);
        k_dupeh<<<(10 * G3 + 255) / 256, 256, 0, stream>>>(whh_b);

        k_gi<<<(NTOT / MB) * (SEQ / TCH) * 2, 256, 0, stream>>>(
            emb, wih_f, bih_f, wih_b, bih_b, gi);
        k_gru2<<<(NTOT / MB) * 2, 256, 0, stream>>>(
            gi, whh_f, bhh_f, whh_b, bhh_b, tup);
    } else {
        // fallback: verified R9 fused kernel
        k_transpose<<<(G3 * DIN + 255) / 256, 256, 0, stream>>>(Wih_f, wcat_f, G3, DIN);
        k_transpose<<<(G3 * HID + 255) / 256, 256, 0, stream>>>(Whh_f, wcat_f + (size_t)DIN * G3, G3, HID);
        k_transpose<<<(G3 * DIN + 255) / 256, 256, 0, stream>>>(Wih_b, wcat_b, G3, DIN);
        k_transpose<<<(G3 * HID + 255) / 256, 256, 0, stream>>>(Whh_b, wcat_b + (size_t)DIN * G3, G3, HID);

        k_gruF<<<(NTOT / MB) * 2, 256, 0, stream>>>(emb,
            wcat_f, bih_f, bhh_f,
            wcat_b, bih_b, bhh_b, tup);
    }

    k_wordattn<<<NTOT, 256, 0, stream>>>(tup, attw, sen_a, sen_r, repre, sbuf);

    k_bag<<<NBAG, 256, 0, stream>>>(repre, sbuf, rel, sen_d, ybatch, out, bagloss);

    k_final<<<1, 64, 0, stream>>>(bagloss, out);
}